// Round 16
// baseline (162.831 us; speedup 1.0000x reference)
//
#include <hip/hip_runtime.h>

typedef __attribute__((ext_vector_type(8))) short bf16x8;
typedef __attribute__((ext_vector_type(4))) float f32x4;
typedef __attribute__((ext_vector_type(2))) float f32x2;

#define MFMA16(a, b, c) __builtin_amdgcn_mfma_f32_16x16x32_bf16(a, b, c, 0, 0, 0)

__device__ __forceinline__ unsigned int cvtpk(float lo, float hi) {
  unsigned int r;
  asm("v_cvt_pk_bf16_f32 %0, %1, %2" : "=v"(r) : "v"(lo), "v"(hi));
  return r;
}
__device__ __forceinline__ float exp2fast(float x) {
  float r;
  asm("v_exp_f32 %0, %1" : "=v"(r) : "v"(x));
  return r;
}
__device__ __forceinline__ unsigned short f2bf(float f) {
  union { float f; unsigned int u; } x; x.f = f;
  unsigned int u = x.u;
  return (unsigned short)((u + 0x7FFFu + ((u >> 16) & 1u)) >> 16);
}
__device__ __forceinline__ bf16x8 mk8(unsigned int w0, unsigned int w1,
                                      unsigned int w2, unsigned int w3) {
  union { unsigned int w[4]; bf16x8 v; } u;
  u.w[0] = w0; u.w[1] = w1; u.w[2] = w2; u.w[3] = w3;
  return u.v;
}

// log2(e)/sqrt(512): folds softmax scale AND exp->exp2 conversion into Q.
#define CSCALE 0.0637669439631016f

// ---------------------------------------------------------------------------
// Fused projection GEMMs: Y = X @ W^T + bias, tile 64x64, bf16 MFMA.
// blockIdx.z selects mode:
//  0: QU = (Y+u_bias)*CSCALE, QV = (Y+v_bias)*CSCALE, layout [b*16+h][l][32]
//  1: K,  layout [b*16+h][l][32]
//  2: V sigma-permuted transposed [b*16+h][32][l'] (l' permuted per 32-block)
//  3: P,  layout [h][t][32]  (M=2048, only blockIdx.x<32 active)
// ---------------------------------------------------------------------------
__global__ __launch_bounds__(256) void proj_fused(
    const float* __restrict__ Xq, const float* __restrict__ Xk,
    const float* __restrict__ Xv, const float* __restrict__ Xp,
    const float* __restrict__ Wq, const float* __restrict__ Wk,
    const float* __restrict__ Wv, const float* __restrict__ Wp,
    const float* __restrict__ bq, const float* __restrict__ bk,
    const float* __restrict__ bv,
    const float* __restrict__ ub, const float* __restrict__ vb,
    unsigned short* __restrict__ QU, unsigned short* __restrict__ QV,
    unsigned short* __restrict__ Kb, unsigned short* __restrict__ Vs,
    unsigned short* __restrict__ Pb)
{
  const int mode = blockIdx.z;
  if (mode == 3 && blockIdx.x >= 32) return;
  const float* X = (mode == 0) ? Xq : (mode == 1) ? Xk : (mode == 2) ? Xv : Xp;
  const float* W = (mode == 0) ? Wq : (mode == 1) ? Wk : (mode == 2) ? Wv : Wp;
  const float* bias = (mode == 0) ? bq : (mode == 1) ? bk : (mode == 2) ? bv : nullptr;

  __shared__ __align__(16) unsigned short As[64][40];
  __shared__ __align__(16) unsigned short Bs[64][40];
  const int i0 = blockIdx.x * 64;
  const int o0 = blockIdx.y * 64;
  const int tid = threadIdx.x;
  const int w = tid >> 6, lane = tid & 63, g = lane >> 4, ln = lane & 15;

  f32x4 acc[4];
  #pragma unroll
  for (int n = 0; n < 4; ++n) acc[n] = (f32x4){0.f, 0.f, 0.f, 0.f};

  const int srow = tid >> 2;
  const int scol = (tid & 3) * 8;

  for (int k0 = 0; k0 < 512; k0 += 32) {
    if (k0) __syncthreads();
    {
      const float* sa = X + (size_t)(i0 + srow) * 512 + k0 + scol;
      f32x4 a0 = *(const f32x4*)sa;
      f32x4 a1 = *(const f32x4*)(sa + 4);
      uint4 av;
      av.x = cvtpk(a0[0], a0[1]); av.y = cvtpk(a0[2], a0[3]);
      av.z = cvtpk(a1[0], a1[1]); av.w = cvtpk(a1[2], a1[3]);
      *(uint4*)&As[srow][scol] = av;

      const float* sb = W + (size_t)(o0 + srow) * 512 + k0 + scol;
      f32x4 b0 = *(const f32x4*)sb;
      f32x4 b1 = *(const f32x4*)(sb + 4);
      uint4 bv2;
      bv2.x = cvtpk(b0[0], b0[1]); bv2.y = cvtpk(b0[2], b0[3]);
      bv2.z = cvtpk(b1[0], b1[1]); bv2.w = cvtpk(b1[2], b1[3]);
      *(uint4*)&Bs[srow][scol] = bv2;
    }
    __syncthreads();
    const bf16x8 af = *(const bf16x8*)&As[w * 16 + ln][g * 8];
    #pragma unroll
    for (int n = 0; n < 4; ++n) {
      const bf16x8 bfv = *(const bf16x8*)&Bs[n * 16 + ln][g * 8];
      acc[n] = MFMA16(af, bfv, acc[n]);
    }
  }

  #pragma unroll
  for (int n = 0; n < 4; ++n) {
    const int o = o0 + n * 16 + ln;
    const float bval = bias ? bias[o] : 0.f;
    const int h = o >> 5, d = o & 31;
    #pragma unroll
    for (int r = 0; r < 4; ++r) {
      const int i = i0 + w * 16 + 4 * g + r;  // C/D: row=4*(l>>4)+r, col=l&15
      const float y = acc[n][r] + bval;
      if (mode == 0) {
        const int b = i >> 11, li = i & 2047;
        const size_t a = (((size_t)(b * 16 + h)) * 2048 + li) * 32 + d;
        QU[a] = f2bf(CSCALE * (y + ub[o]));
        QV[a] = f2bf(CSCALE * (y + vb[o]));
      } else if (mode == 1) {
        const int b = i >> 11, li = i & 2047;
        const size_t a = (((size_t)(b * 16 + h)) * 2048 + li) * 32 + d;
        Kb[a] = f2bf(y);
      } else if (mode == 2) {
        const int b = i >> 11, li = i & 2047;
        const int blk = li >> 5, bb = li & 31;
        // inverse sigma: j<16 -> k=(j>>2)*8+(j&3); j>=16 -> k=((j-16)>>2)*8+4+((j-16)&3)
        const int k = (bb < 16) ? (((bb >> 2) << 3) + (bb & 3))
                                : ((((bb - 16) >> 2) << 3) + 4 + ((bb - 16) & 3));
        const size_t a = (((size_t)(b * 16 + h)) * 32 + d) * 2048 + (blk << 5) + k;
        Vs[a] = f2bf(y);
      } else {
        Pb[((size_t)h * 2048 + i) * 32 + d] = f2bf(y);
      }
    }
  }
}

// ---------------------------------------------------------------------------
// Fused relative attention. One WG = (b, h, 64 query rows), 4 waves (256 thr).
// QBLK=64 (was 32): halves WG count again -> halves K/V/P VMEM instruction
// issue (TA-throughput lever, confirmed by R15). Four query groups per wave:
// group go in {0,16,32,48}, queries i0+go+ln (U rows go+ln).
// fp8 shifted-diagonal U (row r, byte col = t + r + 1, stride 2116; max col
// 2111 < 2116 proven): reads are row-independent (B col = j-i0 at row qr+1,
// A col = j-i0+2048 at row qr), 4-aligned. Sentinel col r = (t=-1) -> 0,
// rows 1..64. Row-64 gate: t0 <= 1982-i0 (max t read = 2047-(i0+63)-2).
// LDS 155 KB -> 1 WG/CU (1 wave/SIMD; per-wave issue density doubled).
// ---------------------------------------------------------------------------
__global__ __launch_bounds__(256, 1) void attn_kernel(
    const unsigned short* __restrict__ QU, const unsigned short* __restrict__ QV,
    const unsigned short* __restrict__ Kb, const unsigned short* __restrict__ Vs,
    const unsigned short* __restrict__ Pb, unsigned short* __restrict__ CTX)
{
  __shared__ __align__(16) unsigned char U8[65 * 2116];  // 137540 B
  __shared__ __align__(16) float sacc[4][16][64];        // 16384 B
  __shared__ float slx[4][64];                           // 1024 B

  // XCD-aware bijective swizzle: 1024 WGs, 128 slots/XCD, 4 bh per XCD.
  const int n = blockIdx.y * 32 + blockIdx.x;
  const int xcd = n & 7, slot = n >> 3;
  const int bh = (xcd << 2) | (slot >> 5);
  const int i0 = (slot & 31) * 64;
  const int h = bh & 15;
  const int b = bh >> 4;
  const int tid = threadIdx.x;
  const int w = tid >> 6, lane = tid & 63, g = lane >> 4, ln = lane & 15;

  const unsigned short* QUp = QU + (size_t)bh * 65536;
  const unsigned short* QVp = QV + (size_t)bh * 65536;
  const unsigned short* Kp  = Kb + (size_t)bh * 65536;
  const unsigned short* Vp  = Vs + (size_t)bh * 65536;
  const unsigned short* Pp  = Pb + (size_t)h * 65536;

  const f32x4 fz = (f32x4){0.f, 0.f, 0.f, 0.f};

  bf16x8 quf[4], qvf[4];
  #pragma unroll
  for (int go = 0; go < 4; ++go) {
    quf[go] = *(const bf16x8*)(QUp + (size_t)(i0 + go * 16 + ln) * 32 + g * 8);
    qvf[go] = *(const bf16x8*)(QVp + (size_t)(i0 + go * 16 + ln) * 32 + g * 8);
  }
  const int r64 = (i0 + 64 < 2048) ? (i0 + 64) : 2047;  // last tile: never read
  const bf16x8 qv64 = *(const bf16x8*)(QVp + (size_t)r64 * 32 + g * 8);

  // zero sentinels: row r, byte col r == (t=-1) for rows 1..64
  if (tid < 64) U8[(tid + 1) * 2116 + (tid + 1)] = 0;

  // ---- Phase 1: build U (fp8, diagonal), rows {go+ln}, row 64; P ring 4 ----
  const unsigned short* Pb0 = Pp + (size_t)(w * 16 + ln) * 32 + g * 8;
  bf16x8 pfb0 = *(const bf16x8*)(Pb0);
  bf16x8 pfb1 = *(const bf16x8*)(Pb0 + 64 * 32);
  bf16x8 pfb2 = *(const bf16x8*)(Pb0 + 128 * 32);
  bf16x8 pfb3 = *(const bf16x8*)(Pb0 + 192 * 32);
  for (int itb = 0; itb < 8; ++itb) {
    #pragma unroll
    for (int k = 0; k < 4; ++k) {
      const int itt = itb * 4 + k;
      const int t0 = itt * 64 + w * 16;
      bf16x8 cur;
      if (k == 0) cur = pfb0; else if (k == 1) cur = pfb1;
      else if (k == 2) cur = pfb2; else cur = pfb3;
      if (itb < 7) {
        const bf16x8 nx = *(const bf16x8*)(Pb0 + (size_t)((itt + 4) * 64) * 32);
        if (k == 0) pfb0 = nx; else if (k == 1) pfb1 = nx;
        else if (k == 2) pfb2 = nx; else pfb3 = nx;
      }
      #pragma unroll
      for (int go = 0; go < 4; ++go) {
        f32x4 u0 = MFMA16(cur, qvf[go], fz);   // U[go*16+ln][t0+4g+r]
        unsigned int pk = __builtin_amdgcn_cvt_pk_fp8_f32(u0[0], u0[1], 0u, false);
        pk = __builtin_amdgcn_cvt_pk_fp8_f32(u0[2], u0[3], pk, true);
        unsigned char* wp = U8 + (go * 16 + ln) * 2116 + (go * 16 + ln) + 1 + 4 * g + t0;
        wp[0] = (unsigned char)(pk & 0xFFu);
        wp[1] = (unsigned char)((pk >> 8) & 0xFFu);
        wp[2] = (unsigned char)((pk >> 16) & 0xFFu);
        wp[3] = (unsigned char)(pk >> 24);
      }
      if (t0 <= 1982 - i0) {            // row 64 only read for t <= 1982-i0
        f32x4 u2 = MFMA16(cur, qv64, fz);
        if (ln == 0) {
          unsigned int qk = __builtin_amdgcn_cvt_pk_fp8_f32(u2[0], u2[1], 0u, false);
          qk = __builtin_amdgcn_cvt_pk_fp8_f32(u2[2], u2[3], qk, true);
          unsigned char* wq = U8 + 64 * 2116 + t0 + 4 * g + 65;
          wq[0] = (unsigned char)(qk & 0xFFu);
          wq[1] = (unsigned char)((qk >> 8) & 0xFFu);
          wq[2] = (unsigned char)((qk >> 16) & 0xFFu);
          wq[3] = (unsigned char)(qk >> 24);
        }
      }
    }
  }
  __syncthreads();

  // ---- Phase 2: j in [w*512, (w+1)*512), 8 iters of 64, 4 query groups ----
  f32x4 acc[4][2], accl[4];
  #pragma unroll
  for (int go = 0; go < 4; ++go) { acc[go][0] = fz; acc[go][1] = fz; accl[go] = fz; }
  const bf16x8 ones = mk8(0x3F803F80u, 0x3F803F80u, 0x3F803F80u, 0x3F803F80u);

  const unsigned short* kp = Kp + (size_t)(w * 512 + ln) * 32 + g * 8;
  bf16x8 kf[4];
  #pragma unroll
  for (int q = 0; q < 4; ++q) kf[q] = *(const bf16x8*)(kp + q * 512);

  const unsigned short* vpb = Vp + (size_t)ln * 2048 + w * 512 + 8 * g;
  bf16x8 vf00 = *(const bf16x8*)vpb;
  bf16x8 vf01 = *(const bf16x8*)(vpb + 32);
  bf16x8 vf10 = *(const bf16x8*)(vpb + 16 * 2048);
  bf16x8 vf11 = *(const bf16x8*)(vpb + 16 * 2048 + 32);

  for (int it = 0; it < 8; ++it) {
    const int jc = w * 512 + it * 64;
    const int jcg = jc + 4 * g;
    const int cb = jcg - i0;   // B-side byte col; A-side = cb + 2048

    float pv[4][16];
    if (jc > i0 + 63) {              // pure B-side, all groups
      #pragma unroll
      for (int go = 0; go < 4; ++go) {
        const unsigned char* bb = U8 + (go * 16 + ln + 1) * 2116 + cb;
        #pragma unroll
        for (int q = 0; q < 4; ++q) {
          const int dv = *(const int*)(bb + 16 * q);
          const f32x2 lo = __builtin_amdgcn_cvt_pk_f32_fp8(dv, false);
          const f32x2 hi = __builtin_amdgcn_cvt_pk_f32_fp8(dv, true);
          pv[go][4 * q + 0] = lo[0]; pv[go][4 * q + 1] = lo[1];
          pv[go][4 * q + 2] = hi[0]; pv[go][4 * q + 3] = hi[1];
        }
      }
    } else if (jc + 75 <= i0) {      // pure A-side, all groups
      #pragma unroll
      for (int go = 0; go < 4; ++go) {
        const unsigned char* aa = U8 + (go * 16 + ln) * 2116 + cb + 2048;
        #pragma unroll
        for (int q = 0; q < 4; ++q) {
          const int dv = *(const int*)(aa + 16 * q);
          const f32x2 lo = __builtin_amdgcn_cvt_pk_f32_fp8(dv, false);
          const f32x2 hi = __builtin_amdgcn_cvt_pk_f32_fp8(dv, true);
          pv[go][4 * q + 0] = lo[0]; pv[go][4 * q + 1] = lo[1];
          pv[go][4 * q + 2] = hi[0]; pv[go][4 * q + 3] = hi[1];
        }
      }
    } else {                         // mixed (<=3 iters per wave)
      #pragma unroll
      for (int go = 0; go < 4; ++go) {
        const int bA = (go * 16 + ln) * 2116 + cb + 2048;
        const int bB = (go * 16 + ln + 1) * 2116 + cb;
        const int djg = i0 + go * 16 + ln - jcg;
        #pragma unroll
        for (int e = 0; e < 16; ++e) {
          const int co = ((e >> 2) << 4) + (e & 3);
          const unsigned int byte = U8[(co <= djg ? bA : bB) + co];
          pv[go][e] = __builtin_amdgcn_cvt_f32_fp8(byte, 0);
        }
      }
    }

    f32x4 st[4][4];
    __builtin_amdgcn_s_setprio(1);
    #pragma unroll
    for (int go = 0; go < 4; ++go) {
      #pragma unroll
      for (int q = 0; q < 4; ++q) st[go][q] = MFMA16(kf[q], quf[go], fz);
    }
    __builtin_amdgcn_s_setprio(0);

    bf16x8 vn0, vn1, vn2, vn3;
    if (it < 7) {  // prefetch next K tile + V into next-regs
      kp += 64 * 32;
      #pragma unroll
      for (int q = 0; q < 4; ++q) kf[q] = *(const bf16x8*)(kp + q * 512);
      const unsigned short* vp2 = vpb + 64;
      vn0 = *(const bf16x8*)vp2;
      vn1 = *(const bf16x8*)(vp2 + 32);
      vn2 = *(const bf16x8*)(vp2 + 16 * 2048);
      vn3 = *(const bf16x8*)(vp2 + 16 * 2048 + 32);
    }

    float p[4][16];
    #pragma unroll
    for (int go = 0; go < 4; ++go) {
      #pragma unroll
      for (int e = 0; e < 16; ++e)
        p[go][e] = exp2fast(st[go][e >> 2][e & 3] + pv[go][e]);
    }

    bf16x8 pfr[4][2];
    #pragma unroll
    for (int go = 0; go < 4; ++go) {
      pfr[go][0] = mk8(cvtpk(p[go][0], p[go][1]), cvtpk(p[go][2], p[go][3]),
                       cvtpk(p[go][4], p[go][5]), cvtpk(p[go][6], p[go][7]));
      pfr[go][1] = mk8(cvtpk(p[go][8], p[go][9]), cvtpk(p[go][10], p[go][11]),
                       cvtpk(p[go][12], p[go][13]), cvtpk(p[go][14], p[go][15]));
    }

    __builtin_amdgcn_s_setprio(1);
    #pragma unroll
    for (int go = 0; go < 4; ++go) {
      acc[go][0] = MFMA16(vf00, pfr[go][0], acc[go][0]);   // d-block 0
      acc[go][0] = MFMA16(vf01, pfr[go][1], acc[go][0]);
      acc[go][1] = MFMA16(vf10, pfr[go][0], acc[go][1]);   // d-block 1
      acc[go][1] = MFMA16(vf11, pfr[go][1], acc[go][1]);
      accl[go] = MFMA16(ones, pfr[go][0], accl[go]);       // sum of p
      accl[go] = MFMA16(ones, pfr[go][1], accl[go]);
    }
    __builtin_amdgcn_s_setprio(0);

    if (it < 7) {
      vpb += 64;
      vf00 = vn0; vf01 = vn1; vf10 = vn2; vf11 = vn3;
    }
  }

  // ---- two-pass cross-wave combine (m=0: plain sums) ----
  if (lane < 16) {
    #pragma unroll
    for (int go = 0; go < 4; ++go) slx[w][go * 16 + lane] = accl[go][0];
  }
  #pragma unroll
  for (int go = 0; go < 4; ++go) {
    #pragma unroll
    for (int r = 0; r < 4; ++r)
      sacc[w][4 * g + r][go * 16 + ln] = acc[go][0][r];
  }
  __syncthreads();

  for (int pp = tid; pp < 1024; pp += 256) {   // pass 1: d 0..15
    const int d = pp >> 6, ii = pp & 63;
    const float Lt = (slx[0][ii] + slx[1][ii]) + (slx[2][ii] + slx[3][ii]);
    const float val = (sacc[0][d][ii] + sacc[1][d][ii]) +
                      (sacc[2][d][ii] + sacc[3][d][ii]);
    CTX[((size_t)(b * 2048 + i0 + ii)) * 512 + h * 32 + d] = f2bf(val / Lt);
  }
  __syncthreads();
  #pragma unroll
  for (int go = 0; go < 4; ++go) {
    #pragma unroll
    for (int r = 0; r < 4; ++r)
      sacc[w][4 * g + r][go * 16 + ln] = acc[go][1][r];
  }
  __syncthreads();
  for (int pp = tid; pp < 1024; pp += 256) {   // pass 2: d 16..31
    const int d = pp >> 6, ii = pp & 63;
    const float Lt = (slx[0][ii] + slx[1][ii]) + (slx[2][ii] + slx[3][ii]);
    const float val = (sacc[0][d][ii] + sacc[1][d][ii]) +
                      (sacc[2][d][ii] + sacc[3][d][ii]);
    CTX[((size_t)(b * 2048 + i0 + ii)) * 512 + h * 32 + 16 + d] = f2bf(val / Lt);
  }
}

// ---------------------------------------------------------------------------
// Output GEMM: out = CTX(bf16) @ Wo^T + bo, fp32 out.
// ---------------------------------------------------------------------------
__global__ __launch_bounds__(256) void out_gemm(
    const unsigned short* __restrict__ A, const float* __restrict__ W,
    const float* __restrict__ bias, float* __restrict__ out)
{
  __shared__ __align__(16) unsigned short As[64][40];
  __shared__ __align__(16) unsigned short Bs[64][40];
  const int i0 = blockIdx.x * 64;
  const int o0 = blockIdx.y * 64;
  const int tid = threadIdx.x;
  const int w = tid >> 6, lane = tid & 63, g = lane >> 4, ln = lane & 15;

  f32x4 acc[4];
  #pragma unroll
  for (int n = 0; n < 4; ++n) acc[n] = (f32x4){0.f, 0.f, 0.f, 0.f};

  const int srow = tid >> 2;
  const int scol = (tid & 3) * 8;

  for (int k0 = 0; k0 < 512; k0 += 32) {
    if (k0) __syncthreads();
    *(bf16x8*)&As[srow][scol] = *(const bf16x8*)(A + (size_t)(i0 + srow) * 512 + k0 + scol);
    {
      const float* sb = W + (size_t)(o0 + srow) * 512 + k0 + scol;
      f32x4 b0 = *(const f32x4*)sb;
      f32x4 b1 = *(const f32x4*)(sb + 4);
      uint4 bv2;
      bv2.x = cvtpk(b0[0], b0[1]); bv2.y = cvtpk(b0[2], b0[3]);
      bv2.z = cvtpk(b1[0], b1[1]); bv2.w = cvtpk(b1[2], b1[3]);
      *(uint4*)&Bs[srow][scol] = bv2;
    }
    __syncthreads();
    const bf16x8 af = *(const bf16x8*)&As[w * 16 + ln][g * 8];
    #pragma unroll
    for (int n = 0; n < 4; ++n) {
      const bf16x8 bfv = *(const bf16x8*)&Bs[n * 16 + ln][g * 8];
      acc[n] = MFMA16(af, bfv, acc[n]);
    }
  }

  #pragma unroll
  for (int n = 0; n < 4; ++n) {
    const int o = o0 + n * 16 + ln;
    const float bval = bias[o];
    #pragma unroll
    for (int r = 0; r < 4; ++r) {
      const int i = i0 + w * 16 + 4 * g + r;
      out[(size_t)i * 512 + o] = acc[n][r] + bval;
    }
  }
}

extern "C" void kernel_launch(void* const* d_in, const int* in_sizes, int n_in,
                              void* d_out, int out_size, void* d_ws, size_t ws_size,
                              hipStream_t stream) {
  const float* query = (const float*)d_in[0];
  const float* key_  = (const float*)d_in[1];
  const float* value = (const float*)d_in[2];
  const float* pos   = (const float*)d_in[3];
  const float* Wq = (const float*)d_in[4];
  const float* bq = (const float*)d_in[5];
  const float* Wk = (const float*)d_in[6];
  const float* bk = (const float*)d_in[7];
  const float* Wv = (const float*)d_in[8];
  const float* bv = (const float*)d_in[9];
  const float* Wp = (const float*)d_in[10];
  const float* ub = (const float*)d_in[11];
  const float* vbias = (const float*)d_in[12];
  const float* Wo = (const float*)d_in[13];
  const float* bo = (const float*)d_in[14];

  char* ws = (char*)d_ws;
  unsigned short* QU  = (unsigned short*)(ws);
  unsigned short* QV  = (unsigned short*)(ws + 4194304);
  unsigned short* Kb  = (unsigned short*)(ws + 2 * 4194304);
  unsigned short* Vs  = (unsigned short*)(ws + 3 * 4194304);
  unsigned short* Pb  = (unsigned short*)(ws + 4 * 4194304);
  unsigned short* CTX = (unsigned short*)(ws + 4 * 4194304 + 2097152);

  proj_fused<<<dim3(64, 8, 4), dim3(256), 0, stream>>>(
      query, key_, value, pos, Wq, Wk, Wv, Wp, bq, bk, bv, ub, vbias,
      QU, QV, Kb, Vs, Pb);
  attn_kernel<<<dim3(32, 32), dim3(256), 0, stream>>>(QU, QV, Kb, Vs, Pb, CTX);
  out_gemm<<<dim3(64, 8), dim3(256), 0, stream>>>(CTX, Wo, bo, (float*)d_out);
}

// Round 17
// 135.427 us; speedup vs baseline: 1.2024x; 1.2024x over previous
//
#include <hip/hip_runtime.h>

typedef __attribute__((ext_vector_type(8))) short bf16x8;
typedef __attribute__((ext_vector_type(4))) float f32x4;
typedef __attribute__((ext_vector_type(2))) float f32x2;

#define MFMA16(a, b, c) __builtin_amdgcn_mfma_f32_16x16x32_bf16(a, b, c, 0, 0, 0)

__device__ __forceinline__ unsigned int cvtpk(float lo, float hi) {
  unsigned int r;
  asm("v_cvt_pk_bf16_f32 %0, %1, %2" : "=v"(r) : "v"(lo), "v"(hi));
  return r;
}
__device__ __forceinline__ float exp2fast(float x) {
  float r;
  asm("v_exp_f32 %0, %1" : "=v"(r) : "v"(x));
  return r;
}
__device__ __forceinline__ unsigned short f2bf(float f) {
  union { float f; unsigned int u; } x; x.f = f;
  unsigned int u = x.u;
  return (unsigned short)((u + 0x7FFFu + ((u >> 16) & 1u)) >> 16);
}
__device__ __forceinline__ bf16x8 mk8(unsigned int w0, unsigned int w1,
                                      unsigned int w2, unsigned int w3) {
  union { unsigned int w[4]; bf16x8 v; } u;
  u.w[0] = w0; u.w[1] = w1; u.w[2] = w2; u.w[3] = w3;
  return u.v;
}

// log2(e)/sqrt(512): folds softmax scale AND exp->exp2 conversion into Q.
#define CSCALE 0.0637669439631016f

// ---------------------------------------------------------------------------
// Fused projection GEMMs: Y = X @ W^T + bias, tile 128x64 (BM=128 BN=64
// BK=32, 4 waves, acc[2][4] per wave -> 2x MFMA-per-barrier density vs 64x64).
// blockIdx.z selects mode:
//  0: QU = (Y+u_bias)*CSCALE, QV = (Y+v_bias)*CSCALE, layout [b*16+h][l][32]
//  1: K,  layout [b*16+h][l][32]
//  2: V sigma-permuted transposed [b*16+h][32][l'] (l' permuted per 32-block)
//  3: P,  layout [h][t][32]  (M=2048, only blockIdx.x<16 active)
// ---------------------------------------------------------------------------
__global__ __launch_bounds__(256) void proj_fused(
    const float* __restrict__ Xq, const float* __restrict__ Xk,
    const float* __restrict__ Xv, const float* __restrict__ Xp,
    const float* __restrict__ Wq, const float* __restrict__ Wk,
    const float* __restrict__ Wv, const float* __restrict__ Wp,
    const float* __restrict__ bq, const float* __restrict__ bk,
    const float* __restrict__ bv,
    const float* __restrict__ ub, const float* __restrict__ vb,
    unsigned short* __restrict__ QU, unsigned short* __restrict__ QV,
    unsigned short* __restrict__ Kb, unsigned short* __restrict__ Vs,
    unsigned short* __restrict__ Pb)
{
  const int mode = blockIdx.z;
  if (mode == 3 && blockIdx.x >= 16) return;
  const float* X = (mode == 0) ? Xq : (mode == 1) ? Xk : (mode == 2) ? Xv : Xp;
  const float* W = (mode == 0) ? Wq : (mode == 1) ? Wk : (mode == 2) ? Wv : Wp;
  const float* bias = (mode == 0) ? bq : (mode == 1) ? bk : (mode == 2) ? bv : nullptr;

  __shared__ __align__(16) unsigned short As[128][40];
  __shared__ __align__(16) unsigned short Bs[64][40];
  const int i0 = blockIdx.x * 128;
  const int o0 = blockIdx.y * 64;
  const int tid = threadIdx.x;
  const int w = tid >> 6, lane = tid & 63, g = lane >> 4, ln = lane & 15;

  f32x4 acc[2][4];
  #pragma unroll
  for (int rf = 0; rf < 2; ++rf)
    #pragma unroll
    for (int n = 0; n < 4; ++n) acc[rf][n] = (f32x4){0.f, 0.f, 0.f, 0.f};

  const int srow = tid >> 2;          // 0..63
  const int scol = (tid & 3) * 8;

  for (int k0 = 0; k0 < 512; k0 += 32) {
    if (k0) __syncthreads();
    {
      const float* sa = X + (size_t)(i0 + srow) * 512 + k0 + scol;
      f32x4 a0 = *(const f32x4*)sa;
      f32x4 a1 = *(const f32x4*)(sa + 4);
      uint4 av;
      av.x = cvtpk(a0[0], a0[1]); av.y = cvtpk(a0[2], a0[3]);
      av.z = cvtpk(a1[0], a1[1]); av.w = cvtpk(a1[2], a1[3]);
      *(uint4*)&As[srow][scol] = av;

      const float* sa2 = X + (size_t)(i0 + 64 + srow) * 512 + k0 + scol;
      f32x4 a2 = *(const f32x4*)sa2;
      f32x4 a3 = *(const f32x4*)(sa2 + 4);
      uint4 av2;
      av2.x = cvtpk(a2[0], a2[1]); av2.y = cvtpk(a2[2], a2[3]);
      av2.z = cvtpk(a3[0], a3[1]); av2.w = cvtpk(a3[2], a3[3]);
      *(uint4*)&As[64 + srow][scol] = av2;

      const float* sb = W + (size_t)(o0 + srow) * 512 + k0 + scol;
      f32x4 b0 = *(const f32x4*)sb;
      f32x4 b1 = *(const f32x4*)(sb + 4);
      uint4 bv2;
      bv2.x = cvtpk(b0[0], b0[1]); bv2.y = cvtpk(b0[2], b0[3]);
      bv2.z = cvtpk(b1[0], b1[1]); bv2.w = cvtpk(b1[2], b1[3]);
      *(uint4*)&Bs[srow][scol] = bv2;
    }
    __syncthreads();
    const bf16x8 af0 = *(const bf16x8*)&As[w * 32 + ln][g * 8];
    const bf16x8 af1 = *(const bf16x8*)&As[w * 32 + 16 + ln][g * 8];
    #pragma unroll
    for (int n = 0; n < 4; ++n) {
      const bf16x8 bfv = *(const bf16x8*)&Bs[n * 16 + ln][g * 8];
      acc[0][n] = MFMA16(af0, bfv, acc[0][n]);
      acc[1][n] = MFMA16(af1, bfv, acc[1][n]);
    }
  }

  #pragma unroll
  for (int rf = 0; rf < 2; ++rf) {
    #pragma unroll
    for (int n = 0; n < 4; ++n) {
      const int o = o0 + n * 16 + ln;
      const float bval = bias ? bias[o] : 0.f;
      const int h = o >> 5, d = o & 31;
      #pragma unroll
      for (int r = 0; r < 4; ++r) {
        const int i = i0 + w * 32 + rf * 16 + 4 * g + r;  // C/D: row=4g+r, col=ln
        const float y = acc[rf][n][r] + bval;
        if (mode == 0) {
          const int b = i >> 11, li = i & 2047;
          const size_t a = (((size_t)(b * 16 + h)) * 2048 + li) * 32 + d;
          QU[a] = f2bf(CSCALE * (y + ub[o]));
          QV[a] = f2bf(CSCALE * (y + vb[o]));
        } else if (mode == 1) {
          const int b = i >> 11, li = i & 2047;
          const size_t a = (((size_t)(b * 16 + h)) * 2048 + li) * 32 + d;
          Kb[a] = f2bf(y);
        } else if (mode == 2) {
          const int b = i >> 11, li = i & 2047;
          const int blk = li >> 5, bb = li & 31;
          // inverse sigma: j<16 -> k=(j>>2)*8+(j&3); j>=16 -> k=((j-16)>>2)*8+4+((j-16)&3)
          const int k = (bb < 16) ? (((bb >> 2) << 3) + (bb & 3))
                                  : ((((bb - 16) >> 2) << 3) + 4 + ((bb - 16) & 3));
          const size_t a = (((size_t)(b * 16 + h)) * 32 + d) * 2048 + (blk << 5) + k;
          Vs[a] = f2bf(y);
        } else {
          Pb[((size_t)h * 2048 + i) * 32 + d] = f2bf(y);
        }
      }
    }
  }
}

// ---------------------------------------------------------------------------
// Fused relative attention (R15-passing kernel, byte-exact).
// One WG = (b, h, 32 query rows), 4 waves (256 thr). fp8 shifted-diagonal U.
// ---------------------------------------------------------------------------
__global__ __launch_bounds__(256, 2) void attn_kernel(
    const unsigned short* __restrict__ QU, const unsigned short* __restrict__ QV,
    const unsigned short* __restrict__ Kb, const unsigned short* __restrict__ Vs,
    const unsigned short* __restrict__ Pb, unsigned short* __restrict__ CTX)
{
  __shared__ __align__(16) unsigned char U8[33 * 2084];  // 68772 B
  __shared__ __align__(16) float sacc[4][16][32];        // 8192 B
  __shared__ float slx[4][32];                           // 512 B

  // XCD-aware bijective swizzle: 2048 WGs, 256 slots/XCD, 4 bh per XCD.
  const int n = blockIdx.y * 64 + blockIdx.x;
  const int xcd = n & 7, slot = n >> 3;
  const int bh = (xcd << 2) | (slot >> 6);
  const int i0 = (slot & 63) * 32;
  const int h = bh & 15;
  const int b = bh >> 4;
  const int tid = threadIdx.x;
  const int w = tid >> 6, lane = tid & 63, g = lane >> 4, ln = lane & 15;

  const unsigned short* QUp = QU + (size_t)bh * 65536;
  const unsigned short* QVp = QV + (size_t)bh * 65536;
  const unsigned short* Kp  = Kb + (size_t)bh * 65536;
  const unsigned short* Vp  = Vs + (size_t)bh * 65536;
  const unsigned short* Pp  = Pb + (size_t)h * 65536;

  const f32x4 fz = (f32x4){0.f, 0.f, 0.f, 0.f};

  const bf16x8 quf0 = *(const bf16x8*)(QUp + (size_t)(i0 + ln) * 32 + g * 8);
  const bf16x8 quf1 = *(const bf16x8*)(QUp + (size_t)(i0 + 16 + ln) * 32 + g * 8);
  const bf16x8 qvf0 = *(const bf16x8*)(QVp + (size_t)(i0 + ln) * 32 + g * 8);
  const bf16x8 qvf1 = *(const bf16x8*)(QVp + (size_t)(i0 + 16 + ln) * 32 + g * 8);
  const int r32 = (i0 + 32 < 2048) ? (i0 + 32) : 2047;  // last tile: never read
  const bf16x8 qv32 = *(const bf16x8*)(QVp + (size_t)r32 * 32 + g * 8);

  // zero sentinels: row r, byte col r == (t=-1) for rows 1..32
  if (tid < 32) U8[(tid + 1) * 2084 + (tid + 1)] = 0;

  // ---- Phase 1: build U (fp8, diagonal), rows {ln, ln+16, 32}, P ring 4 ----
  const unsigned short* Pb0 = Pp + (size_t)(w * 16 + ln) * 32 + g * 8;
  bf16x8 pfb0 = *(const bf16x8*)(Pb0);
  bf16x8 pfb1 = *(const bf16x8*)(Pb0 + 64 * 32);
  bf16x8 pfb2 = *(const bf16x8*)(Pb0 + 128 * 32);
  bf16x8 pfb3 = *(const bf16x8*)(Pb0 + 192 * 32);
  const int wr0 = ln * 2084 + 4 * g + ln + 1;          // group0 byte base (+t0)
  const int wr1 = (ln + 16) * 2084 + 4 * g + ln + 17;  // group1 byte base (+t0)
  for (int itb = 0; itb < 8; ++itb) {
    #pragma unroll
    for (int k = 0; k < 4; ++k) {
      const int itt = itb * 4 + k;
      const int t0 = itt * 64 + w * 16;
      bf16x8 cur;
      if (k == 0) cur = pfb0; else if (k == 1) cur = pfb1;
      else if (k == 2) cur = pfb2; else cur = pfb3;
      if (itb < 7) {
        const bf16x8 nx = *(const bf16x8*)(Pb0 + (size_t)((itt + 4) * 64) * 32);
        if (k == 0) pfb0 = nx; else if (k == 1) pfb1 = nx;
        else if (k == 2) pfb2 = nx; else pfb3 = nx;
      }
      {
        f32x4 u0 = MFMA16(cur, qvf0, fz);   // U[ln][t0+4g+r]
        unsigned int pk = __builtin_amdgcn_cvt_pk_fp8_f32(u0[0], u0[1], 0u, false);
        pk = __builtin_amdgcn_cvt_pk_fp8_f32(u0[2], u0[3], pk, true);
        unsigned char* wp = U8 + wr0 + t0;
        wp[0] = (unsigned char)(pk & 0xFFu);
        wp[1] = (unsigned char)((pk >> 8) & 0xFFu);
        wp[2] = (unsigned char)((pk >> 16) & 0xFFu);
        wp[3] = (unsigned char)(pk >> 24);
      }
      {
        f32x4 u1 = MFMA16(cur, qvf1, fz);   // U[ln+16][t0+4g+r]
        unsigned int pk = __builtin_amdgcn_cvt_pk_fp8_f32(u1[0], u1[1], 0u, false);
        pk = __builtin_amdgcn_cvt_pk_fp8_f32(u1[2], u1[3], pk, true);
        unsigned char* wp = U8 + wr1 + t0;
        wp[0] = (unsigned char)(pk & 0xFFu);
        wp[1] = (unsigned char)((pk >> 8) & 0xFFu);
        wp[2] = (unsigned char)((pk >> 16) & 0xFFu);
        wp[3] = (unsigned char)(pk >> 24);
      }
      if (t0 <= 2014 - i0) {            // row 32 only read for t <= 2014-i0
        f32x4 u2 = MFMA16(cur, qv32, fz);
        if (ln == 0) {
          unsigned int qk = __builtin_amdgcn_cvt_pk_fp8_f32(u2[0], u2[1], 0u, false);
          qk = __builtin_amdgcn_cvt_pk_fp8_f32(u2[2], u2[3], qk, true);
          unsigned char* wq = U8 + 32 * 2084 + t0 + 4 * g + 33;
          wq[0] = (unsigned char)(qk & 0xFFu);
          wq[1] = (unsigned char)((qk >> 8) & 0xFFu);
          wq[2] = (unsigned char)((qk >> 16) & 0xFFu);
          wq[3] = (unsigned char)(qk >> 24);
        }
      }
    }
  }
  __syncthreads();

  // ---- Phase 2: j in [w*512, (w+1)*512), 8 iters of 64, 2 query groups ----
  f32x4 acc00 = fz, acc01 = fz, acc10 = fz, acc11 = fz;
  f32x4 accl0 = fz, accl1 = fz;
  const bf16x8 ones = mk8(0x3F803F80u, 0x3F803F80u, 0x3F803F80u, 0x3F803F80u);

  const unsigned short* kp = Kp + (size_t)(w * 512 + ln) * 32 + g * 8;
  bf16x8 kf[4];
  #pragma unroll
  for (int q = 0; q < 4; ++q) kf[q] = *(const bf16x8*)(kp + q * 512);

  const unsigned short* vpb = Vp + (size_t)ln * 2048 + w * 512 + 8 * g;
  bf16x8 vf00 = *(const bf16x8*)vpb;
  bf16x8 vf01 = *(const bf16x8*)(vpb + 32);
  bf16x8 vf10 = *(const bf16x8*)(vpb + 16 * 2048);
  bf16x8 vf11 = *(const bf16x8*)(vpb + 16 * 2048 + 32);

  for (int it = 0; it < 8; ++it) {
    const int jc = w * 512 + it * 64;
    const int jcg = jc + 4 * g;
    const int cb = jcg - i0;   // B-side byte col; A-side = cb + 2048

    float pv0[16], pv1[16];
    if (jc > i0 + 31) {              // pure B-side for both groups
      const unsigned char* b0 = U8 + (ln + 1) * 2084 + cb;
      const unsigned char* b1 = U8 + (ln + 17) * 2084 + cb;
      #pragma unroll
      for (int q = 0; q < 4; ++q) {
        const int d0 = *(const int*)(b0 + 16 * q);
        const f32x2 l0 = __builtin_amdgcn_cvt_pk_f32_fp8(d0, false);
        const f32x2 h0 = __builtin_amdgcn_cvt_pk_f32_fp8(d0, true);
        pv0[4 * q + 0] = l0[0]; pv0[4 * q + 1] = l0[1];
        pv0[4 * q + 2] = h0[0]; pv0[4 * q + 3] = h0[1];
        const int d1 = *(const int*)(b1 + 16 * q);
        const f32x2 l1 = __builtin_amdgcn_cvt_pk_f32_fp8(d1, false);
        const f32x2 h1 = __builtin_amdgcn_cvt_pk_f32_fp8(d1, true);
        pv1[4 * q + 0] = l1[0]; pv1[4 * q + 1] = l1[1];
        pv1[4 * q + 2] = h1[0]; pv1[4 * q + 3] = h1[1];
      }
    } else if (jc + 75 <= i0) {      // pure A-side for both groups
      const unsigned char* a0 = U8 + ln * 2084 + cb + 2048;
      const unsigned char* a1 = U8 + (ln + 16) * 2084 + cb + 2048;
      #pragma unroll
      for (int q = 0; q < 4; ++q) {
        const int d0 = *(const int*)(a0 + 16 * q);
        const f32x2 l0 = __builtin_amdgcn_cvt_pk_f32_fp8(d0, false);
        const f32x2 h0 = __builtin_amdgcn_cvt_pk_f32_fp8(d0, true);
        pv0[4 * q + 0] = l0[0]; pv0[4 * q + 1] = l0[1];
        pv0[4 * q + 2] = h0[0]; pv0[4 * q + 3] = h0[1];
        const int d1 = *(const int*)(a1 + 16 * q);
        const f32x2 l1 = __builtin_amdgcn_cvt_pk_f32_fp8(d1, false);
        const f32x2 h1 = __builtin_amdgcn_cvt_pk_f32_fp8(d1, true);
        pv1[4 * q + 0] = l1[0]; pv1[4 * q + 1] = l1[1];
        pv1[4 * q + 2] = h1[0]; pv1[4 * q + 3] = h1[1];
      }
    } else {                         // mixed (≈2 iters per wave)
      const int bA0 = ln * 2084 + cb + 2048;
      const int bB0 = (ln + 1) * 2084 + cb;
      const int bA1 = (ln + 16) * 2084 + cb + 2048;
      const int bB1 = (ln + 17) * 2084 + cb;
      const int djg0 = i0 + ln - jcg;
      const int djg1 = i0 + 16 + ln - jcg;
      #pragma unroll
      for (int e = 0; e < 16; ++e) {
        const int co = ((e >> 2) << 4) + (e & 3);
        const unsigned int b0 = U8[(co <= djg0 ? bA0 : bB0) + co];
        pv0[e] = __builtin_amdgcn_cvt_f32_fp8(b0, 0);
        const unsigned int b1 = U8[(co <= djg1 ? bA1 : bB1) + co];
        pv1[e] = __builtin_amdgcn_cvt_f32_fp8(b1, 0);
      }
    }

    f32x4 st0[4], st1[4];
    __builtin_amdgcn_s_setprio(1);
    #pragma unroll
    for (int q = 0; q < 4; ++q) {
      st0[q] = MFMA16(kf[q], quf0, fz);
      st1[q] = MFMA16(kf[q], quf1, fz);
    }
    __builtin_amdgcn_s_setprio(0);

    bf16x8 vn0, vn1, vn2, vn3;
    if (it < 7) {  // prefetch next K tile + V into next-regs
      kp += 64 * 32;
      #pragma unroll
      for (int q = 0; q < 4; ++q) kf[q] = *(const bf16x8*)(kp + q * 512);
      const unsigned short* vp2 = vpb + 64;
      vn0 = *(const bf16x8*)vp2;
      vn1 = *(const bf16x8*)(vp2 + 32);
      vn2 = *(const bf16x8*)(vp2 + 16 * 2048);
      vn3 = *(const bf16x8*)(vp2 + 16 * 2048 + 32);
    }

    float p0[16], p1[16];
    #pragma unroll
    for (int e = 0; e < 16; ++e) {
      p0[e] = exp2fast(st0[e >> 2][e & 3] + pv0[e]);
      p1[e] = exp2fast(st1[e >> 2][e & 3] + pv1[e]);
    }

    const bf16x8 pfr00 = mk8(cvtpk(p0[0], p0[1]), cvtpk(p0[2], p0[3]),
                             cvtpk(p0[4], p0[5]), cvtpk(p0[6], p0[7]));
    const bf16x8 pfr01 = mk8(cvtpk(p0[8], p0[9]), cvtpk(p0[10], p0[11]),
                             cvtpk(p0[12], p0[13]), cvtpk(p0[14], p0[15]));
    const bf16x8 pfr10 = mk8(cvtpk(p1[0], p1[1]), cvtpk(p1[2], p1[3]),
                             cvtpk(p1[4], p1[5]), cvtpk(p1[6], p1[7]));
    const bf16x8 pfr11 = mk8(cvtpk(p1[8], p1[9]), cvtpk(p1[10], p1[11]),
                             cvtpk(p1[12], p1[13]), cvtpk(p1[14], p1[15]));

    __builtin_amdgcn_s_setprio(1);
    acc00 = MFMA16(vf00, pfr00, acc00);   // group0, d-block 0
    acc00 = MFMA16(vf01, pfr01, acc00);
    acc01 = MFMA16(vf10, pfr00, acc01);   // group0, d-block 1
    acc01 = MFMA16(vf11, pfr01, acc01);
    acc10 = MFMA16(vf00, pfr10, acc10);   // group1, d-block 0
    acc10 = MFMA16(vf01, pfr11, acc10);
    acc11 = MFMA16(vf10, pfr10, acc11);   // group1, d-block 1
    acc11 = MFMA16(vf11, pfr11, acc11);
    accl0 = MFMA16(ones, pfr00, accl0);   // sum of p, group0
    accl0 = MFMA16(ones, pfr01, accl0);
    accl1 = MFMA16(ones, pfr10, accl1);   // sum of p, group1
    accl1 = MFMA16(ones, pfr11, accl1);
    __builtin_amdgcn_s_setprio(0);

    if (it < 7) {
      vpb += 64;
      vf00 = vn0; vf01 = vn1; vf10 = vn2; vf11 = vn3;
    }
  }

  // ---- two-pass cross-wave combine (m=0: plain sums) ----
  if (lane < 16) { slx[w][lane] = accl0[0]; slx[w][lane + 16] = accl1[0]; }
  #pragma unroll
  for (int r = 0; r < 4; ++r) {
    sacc[w][4 * g + r][ln] = acc00[r];
    sacc[w][4 * g + r][ln + 16] = acc10[r];
  }
  __syncthreads();

  for (int pp = tid; pp < 512; pp += 256) {   // pass 1: d 0..15
    const int d = pp >> 5, ii = pp & 31;
    const float Lt = (slx[0][ii] + slx[1][ii]) + (slx[2][ii] + slx[3][ii]);
    const float val = (sacc[0][d][ii] + sacc[1][d][ii]) +
                      (sacc[2][d][ii] + sacc[3][d][ii]);
    CTX[((size_t)(b * 2048 + i0 + ii)) * 512 + h * 32 + d] = f2bf(val / Lt);
  }
  __syncthreads();
  #pragma unroll
  for (int r = 0; r < 4; ++r) {
    sacc[w][4 * g + r][ln] = acc01[r];
    sacc[w][4 * g + r][ln + 16] = acc11[r];
  }
  __syncthreads();
  for (int pp = tid; pp < 512; pp += 256) {   // pass 2: d 16..31
    const int d = pp >> 5, ii = pp & 31;
    const float Lt = (slx[0][ii] + slx[1][ii]) + (slx[2][ii] + slx[3][ii]);
    const float val = (sacc[0][d][ii] + sacc[1][d][ii]) +
                      (sacc[2][d][ii] + sacc[3][d][ii]);
    CTX[((size_t)(b * 2048 + i0 + ii)) * 512 + h * 32 + 16 + d] = f2bf(val / Lt);
  }
}

// ---------------------------------------------------------------------------
// Output GEMM: out = CTX(bf16) @ Wo^T + bo, fp32 out. Tile 128x64.
// ---------------------------------------------------------------------------
__global__ __launch_bounds__(256) void out_gemm(
    const unsigned short* __restrict__ A, const float* __restrict__ W,
    const float* __restrict__ bias, float* __restrict__ out)
{
  __shared__ __align__(16) unsigned short As[128][40];
  __shared__ __align__(16) unsigned short Bs[64][40];
  const int i0 = blockIdx.x * 128;
  const int o0 = blockIdx.y * 64;
  const int tid = threadIdx.x;
  const int w = tid >> 6, lane = tid & 63, g = lane >> 4, ln = lane & 15;

  f32x4 acc[2][4];
  #pragma unroll
  for (int rf = 0; rf < 2; ++rf)
    #pragma unroll
    for (int n = 0; n < 4; ++n) acc[rf][n] = (f32x4){0.f, 0.f, 0.f, 0.f};

  const int srow = tid >> 2;
  const int scol = (tid & 3) * 8;

  for (int k0 = 0; k0 < 512; k0 += 32) {
    if (k0) __syncthreads();
    *(bf16x8*)&As[srow][scol] =
        *(const bf16x8*)(A + (size_t)(i0 + srow) * 512 + k0 + scol);
    *(bf16x8*)&As[64 + srow][scol] =
        *(const bf16x8*)(A + (size_t)(i0 + 64 + srow) * 512 + k0 + scol);
    {
      const float* sb = W + (size_t)(o0 + srow) * 512 + k0 + scol;
      f32x4 b0 = *(const f32x4*)sb;
      f32x4 b1 = *(const f32x4*)(sb + 4);
      uint4 bv2;
      bv2.x = cvtpk(b0[0], b0[1]); bv2.y = cvtpk(b0[2], b0[3]);
      bv2.z = cvtpk(b1[0], b1[1]); bv2.w = cvtpk(b1[2], b1[3]);
      *(uint4*)&Bs[srow][scol] = bv2;
    }
    __syncthreads();
    const bf16x8 af0 = *(const bf16x8*)&As[w * 32 + ln][g * 8];
    const bf16x8 af1 = *(const bf16x8*)&As[w * 32 + 16 + ln][g * 8];
    #pragma unroll
    for (int n = 0; n < 4; ++n) {
      const bf16x8 bfv = *(const bf16x8*)&Bs[n * 16 + ln][g * 8];
      acc[0][n] = MFMA16(af0, bfv, acc[0][n]);
      acc[1][n] = MFMA16(af1, bfv, acc[1][n]);
    }
  }

  #pragma unroll
  for (int rf = 0; rf < 2; ++rf) {
    #pragma unroll
    for (int n = 0; n < 4; ++n) {
      const int o = o0 + n * 16 + ln;
      const float bval = bias[o];
      #pragma unroll
      for (int r = 0; r < 4; ++r) {
        const int i = i0 + w * 32 + rf * 16 + 4 * g + r;
        out[(size_t)i * 512 + o] = acc[rf][n][r] + bval;
      }
    }
  }
}

extern "C" void kernel_launch(void* const* d_in, const int* in_sizes, int n_in,
                              void* d_out, int out_size, void* d_ws, size_t ws_size,
                              hipStream_t stream) {
  const float* query = (const float*)d_in[0];
  const float* key_  = (const float*)d_in[1];
  const float* value = (const float*)d_in[2];
  const float* pos   = (const float*)d_in[3];
  const float* Wq = (const float*)d_in[4];
  const float* bq = (const float*)d_in[5];
  const float* Wk = (const float*)d_in[6];
  const float* bk = (const float*)d_in[7];
  const float* Wv = (const float*)d_in[8];
  const float* bv = (const float*)d_in[9];
  const float* Wp = (const float*)d_in[10];
  const float* ub = (const float*)d_in[11];
  const float* vbias = (const float*)d_in[12];
  const float* Wo = (const float*)d_in[13];
  const float* bo = (const float*)d_in[14];

  char* ws = (char*)d_ws;
  unsigned short* QU  = (unsigned short*)(ws);
  unsigned short* QV  = (unsigned short*)(ws + 4194304);
  unsigned short* Kb  = (unsigned short*)(ws + 2 * 4194304);
  unsigned short* Vs  = (unsigned short*)(ws + 3 * 4194304);
  unsigned short* Pb  = (unsigned short*)(ws + 4 * 4194304);
  unsigned short* CTX = (unsigned short*)(ws + 4 * 4194304 + 2097152);

  proj_fused<<<dim3(32, 8, 4), dim3(256), 0, stream>>>(
      query, key_, value, pos, Wq, Wk, Wv, Wp, bq, bk, bv, ub, vbias,
      QU, QV, Kb, Vs, Pb);
  attn_kernel<<<dim3(64, 32), dim3(256), 0, stream>>>(QU, QV, Kb, Vs, Pb, CTX);
  out_gemm<<<dim3(32, 8), dim3(256), 0, stream>>>(CTX, Wo, bo, (float*)d_out);
}

// Round 18
// 131.038 us; speedup vs baseline: 1.2426x; 1.0335x over previous
//
#include <hip/hip_runtime.h>

typedef __attribute__((ext_vector_type(8))) short bf16x8;
typedef __attribute__((ext_vector_type(4))) float f32x4;
typedef __attribute__((ext_vector_type(2))) float f32x2;

#define MFMA16(a, b, c) __builtin_amdgcn_mfma_f32_16x16x32_bf16(a, b, c, 0, 0, 0)

__device__ __forceinline__ unsigned int cvtpk(float lo, float hi) {
  unsigned int r;
  asm("v_cvt_pk_bf16_f32 %0, %1, %2" : "=v"(r) : "v"(lo), "v"(hi));
  return r;
}
__device__ __forceinline__ float exp2fast(float x) {
  float r;
  asm("v_exp_f32 %0, %1" : "=v"(r) : "v"(x));
  return r;
}
__device__ __forceinline__ unsigned short f2bf(float f) {
  union { float f; unsigned int u; } x; x.f = f;
  unsigned int u = x.u;
  return (unsigned short)((u + 0x7FFFu + ((u >> 16) & 1u)) >> 16);
}
__device__ __forceinline__ bf16x8 mk8(unsigned int w0, unsigned int w1,
                                      unsigned int w2, unsigned int w3) {
  union { unsigned int w[4]; bf16x8 v; } u;
  u.w[0] = w0; u.w[1] = w1; u.w[2] = w2; u.w[3] = w3;
  return u.v;
}

// log2(e)/sqrt(512): folds softmax scale AND exp->exp2 conversion into Q.
#define CSCALE 0.0637669439631016f

// ---------------------------------------------------------------------------
// Fused projection GEMMs: Y = X @ W^T + bias, tile 128x64.
// blockIdx.z selects mode:
//  0: QU = (Y+u_bias)*CSCALE, QV = (Y+v_bias)*CSCALE, layout [b*16+h][l][32]
//  1: K,  layout [b*16+h][l][32]
//  2: V sigma-permuted transposed [b*16+h][32][l'] (l' permuted per 32-block)
//  3: P,  layout [h][t][32]  (M=2048, only blockIdx.x<16 active)
// ---------------------------------------------------------------------------
__global__ __launch_bounds__(256) void proj_fused(
    const float* __restrict__ Xq, const float* __restrict__ Xk,
    const float* __restrict__ Xv, const float* __restrict__ Xp,
    const float* __restrict__ Wq, const float* __restrict__ Wk,
    const float* __restrict__ Wv, const float* __restrict__ Wp,
    const float* __restrict__ bq, const float* __restrict__ bk,
    const float* __restrict__ bv,
    const float* __restrict__ ub, const float* __restrict__ vb,
    unsigned short* __restrict__ QU, unsigned short* __restrict__ QV,
    unsigned short* __restrict__ Kb, unsigned short* __restrict__ Vs,
    unsigned short* __restrict__ Pb)
{
  const int mode = blockIdx.z;
  if (mode == 3 && blockIdx.x >= 16) return;
  const float* X = (mode == 0) ? Xq : (mode == 1) ? Xk : (mode == 2) ? Xv : Xp;
  const float* W = (mode == 0) ? Wq : (mode == 1) ? Wk : (mode == 2) ? Wv : Wp;
  const float* bias = (mode == 0) ? bq : (mode == 1) ? bk : (mode == 2) ? bv : nullptr;

  __shared__ __align__(16) unsigned short As[128][40];
  __shared__ __align__(16) unsigned short Bs[64][40];
  const int i0 = blockIdx.x * 128;
  const int o0 = blockIdx.y * 64;
  const int tid = threadIdx.x;
  const int w = tid >> 6, lane = tid & 63, g = lane >> 4, ln = lane & 15;

  f32x4 acc[2][4];
  #pragma unroll
  for (int rf = 0; rf < 2; ++rf)
    #pragma unroll
    for (int n = 0; n < 4; ++n) acc[rf][n] = (f32x4){0.f, 0.f, 0.f, 0.f};

  const int srow = tid >> 2;          // 0..63
  const int scol = (tid & 3) * 8;

  for (int k0 = 0; k0 < 512; k0 += 32) {
    if (k0) __syncthreads();
    {
      const float* sa = X + (size_t)(i0 + srow) * 512 + k0 + scol;
      f32x4 a0 = *(const f32x4*)sa;
      f32x4 a1 = *(const f32x4*)(sa + 4);
      uint4 av;
      av.x = cvtpk(a0[0], a0[1]); av.y = cvtpk(a0[2], a0[3]);
      av.z = cvtpk(a1[0], a1[1]); av.w = cvtpk(a1[2], a1[3]);
      *(uint4*)&As[srow][scol] = av;

      const float* sa2 = X + (size_t)(i0 + 64 + srow) * 512 + k0 + scol;
      f32x4 a2 = *(const f32x4*)sa2;
      f32x4 a3 = *(const f32x4*)(sa2 + 4);
      uint4 av2;
      av2.x = cvtpk(a2[0], a2[1]); av2.y = cvtpk(a2[2], a2[3]);
      av2.z = cvtpk(a3[0], a3[1]); av2.w = cvtpk(a3[2], a3[3]);
      *(uint4*)&As[64 + srow][scol] = av2;

      const float* sb = W + (size_t)(o0 + srow) * 512 + k0 + scol;
      f32x4 b0 = *(const f32x4*)sb;
      f32x4 b1 = *(const f32x4*)(sb + 4);
      uint4 bv2;
      bv2.x = cvtpk(b0[0], b0[1]); bv2.y = cvtpk(b0[2], b0[3]);
      bv2.z = cvtpk(b1[0], b1[1]); bv2.w = cvtpk(b1[2], b1[3]);
      *(uint4*)&Bs[srow][scol] = bv2;
    }
    __syncthreads();
    const bf16x8 af0 = *(const bf16x8*)&As[w * 32 + ln][g * 8];
    const bf16x8 af1 = *(const bf16x8*)&As[w * 32 + 16 + ln][g * 8];
    #pragma unroll
    for (int n = 0; n < 4; ++n) {
      const bf16x8 bfv = *(const bf16x8*)&Bs[n * 16 + ln][g * 8];
      acc[0][n] = MFMA16(af0, bfv, acc[0][n]);
      acc[1][n] = MFMA16(af1, bfv, acc[1][n]);
    }
  }

  #pragma unroll
  for (int rf = 0; rf < 2; ++rf) {
    #pragma unroll
    for (int n = 0; n < 4; ++n) {
      const int o = o0 + n * 16 + ln;
      const float bval = bias ? bias[o] : 0.f;
      const int h = o >> 5, d = o & 31;
      #pragma unroll
      for (int r = 0; r < 4; ++r) {
        const int i = i0 + w * 32 + rf * 16 + 4 * g + r;
        const float y = acc[rf][n][r] + bval;
        if (mode == 0) {
          const int b = i >> 11, li = i & 2047;
          const size_t a = (((size_t)(b * 16 + h)) * 2048 + li) * 32 + d;
          QU[a] = f2bf(CSCALE * (y + ub[o]));
          QV[a] = f2bf(CSCALE * (y + vb[o]));
        } else if (mode == 1) {
          const int b = i >> 11, li = i & 2047;
          const size_t a = (((size_t)(b * 16 + h)) * 2048 + li) * 32 + d;
          Kb[a] = f2bf(y);
        } else if (mode == 2) {
          const int b = i >> 11, li = i & 2047;
          const int blk = li >> 5, bb = li & 31;
          const int k = (bb < 16) ? (((bb >> 2) << 3) + (bb & 3))
                                  : ((((bb - 16) >> 2) << 3) + 4 + ((bb - 16) & 3));
          const size_t a = (((size_t)(b * 16 + h)) * 32 + d) * 2048 + (blk << 5) + k;
          Vs[a] = f2bf(y);
        } else {
          Pb[((size_t)h * 2048 + i) * 32 + d] = f2bf(y);
        }
      }
    }
  }
}

// ---------------------------------------------------------------------------
// Fused relative attention. One WG = (b, h, 32 query rows), 4 waves (256 thr).
// R15 structure with phase 2 SOFTWARE-PIPELINED one iteration deep:
// at iter it we (1) issue the U-gather ds_reads for it+1 (unpack deferred
// past the PV MFMAs), (2) compute QK^T for it+1 from prefetched K, then
// (3) exp/pack/PV for it on register-resident st/pv. Loop fully unrolled so
// the double-buffer rotation dissolves in SSA.
// ---------------------------------------------------------------------------
__global__ __launch_bounds__(256, 2) void attn_kernel(
    const unsigned short* __restrict__ QU, const unsigned short* __restrict__ QV,
    const unsigned short* __restrict__ Kb, const unsigned short* __restrict__ Vs,
    const unsigned short* __restrict__ Pb, unsigned short* __restrict__ CTX)
{
  __shared__ __align__(16) unsigned char U8[33 * 2084];  // 68772 B
  __shared__ __align__(16) float sacc[4][16][32];        // 8192 B
  __shared__ float slx[4][32];                           // 512 B

  // XCD-aware bijective swizzle: 2048 WGs, 256 slots/XCD, 4 bh per XCD.
  const int n = blockIdx.y * 64 + blockIdx.x;
  const int xcd = n & 7, slot = n >> 3;
  const int bh = (xcd << 2) | (slot >> 6);
  const int i0 = (slot & 63) * 32;
  const int h = bh & 15;
  const int b = bh >> 4;
  const int tid = threadIdx.x;
  const int w = tid >> 6, lane = tid & 63, g = lane >> 4, ln = lane & 15;

  const unsigned short* QUp = QU + (size_t)bh * 65536;
  const unsigned short* QVp = QV + (size_t)bh * 65536;
  const unsigned short* Kp  = Kb + (size_t)bh * 65536;
  const unsigned short* Vp  = Vs + (size_t)bh * 65536;
  const unsigned short* Pp  = Pb + (size_t)h * 65536;

  const f32x4 fz = (f32x4){0.f, 0.f, 0.f, 0.f};

  const bf16x8 quf0 = *(const bf16x8*)(QUp + (size_t)(i0 + ln) * 32 + g * 8);
  const bf16x8 quf1 = *(const bf16x8*)(QUp + (size_t)(i0 + 16 + ln) * 32 + g * 8);
  const bf16x8 qvf0 = *(const bf16x8*)(QVp + (size_t)(i0 + ln) * 32 + g * 8);
  const bf16x8 qvf1 = *(const bf16x8*)(QVp + (size_t)(i0 + 16 + ln) * 32 + g * 8);
  const int r32 = (i0 + 32 < 2048) ? (i0 + 32) : 2047;  // last tile: never read
  const bf16x8 qv32 = *(const bf16x8*)(QVp + (size_t)r32 * 32 + g * 8);

  // zero sentinels: row r, byte col r == (t=-1) for rows 1..32
  if (tid < 32) U8[(tid + 1) * 2084 + (tid + 1)] = 0;

  // ---- Phase 1: build U (fp8, diagonal), rows {ln, ln+16, 32}, P ring 4 ----
  const unsigned short* Pb0 = Pp + (size_t)(w * 16 + ln) * 32 + g * 8;
  bf16x8 pfb0 = *(const bf16x8*)(Pb0);
  bf16x8 pfb1 = *(const bf16x8*)(Pb0 + 64 * 32);
  bf16x8 pfb2 = *(const bf16x8*)(Pb0 + 128 * 32);
  bf16x8 pfb3 = *(const bf16x8*)(Pb0 + 192 * 32);
  const int wr0 = ln * 2084 + 4 * g + ln + 1;          // group0 byte base (+t0)
  const int wr1 = (ln + 16) * 2084 + 4 * g + ln + 17;  // group1 byte base (+t0)
  for (int itb = 0; itb < 8; ++itb) {
    #pragma unroll
    for (int k = 0; k < 4; ++k) {
      const int itt = itb * 4 + k;
      const int t0 = itt * 64 + w * 16;
      bf16x8 cur;
      if (k == 0) cur = pfb0; else if (k == 1) cur = pfb1;
      else if (k == 2) cur = pfb2; else cur = pfb3;
      if (itb < 7) {
        const bf16x8 nx = *(const bf16x8*)(Pb0 + (size_t)((itt + 4) * 64) * 32);
        if (k == 0) pfb0 = nx; else if (k == 1) pfb1 = nx;
        else if (k == 2) pfb2 = nx; else pfb3 = nx;
      }
      {
        f32x4 u0 = MFMA16(cur, qvf0, fz);   // U[ln][t0+4g+r]
        unsigned int pk = __builtin_amdgcn_cvt_pk_fp8_f32(u0[0], u0[1], 0u, false);
        pk = __builtin_amdgcn_cvt_pk_fp8_f32(u0[2], u0[3], pk, true);
        unsigned char* wp = U8 + wr0 + t0;
        wp[0] = (unsigned char)(pk & 0xFFu);
        wp[1] = (unsigned char)((pk >> 8) & 0xFFu);
        wp[2] = (unsigned char)((pk >> 16) & 0xFFu);
        wp[3] = (unsigned char)(pk >> 24);
      }
      {
        f32x4 u1 = MFMA16(cur, qvf1, fz);   // U[ln+16][t0+4g+r]
        unsigned int pk = __builtin_amdgcn_cvt_pk_fp8_f32(u1[0], u1[1], 0u, false);
        pk = __builtin_amdgcn_cvt_pk_fp8_f32(u1[2], u1[3], pk, true);
        unsigned char* wp = U8 + wr1 + t0;
        wp[0] = (unsigned char)(pk & 0xFFu);
        wp[1] = (unsigned char)((pk >> 8) & 0xFFu);
        wp[2] = (unsigned char)((pk >> 16) & 0xFFu);
        wp[3] = (unsigned char)(pk >> 24);
      }
      if (t0 <= 2014 - i0) {            // row 32 only read for t <= 2014-i0
        f32x4 u2 = MFMA16(cur, qv32, fz);
        if (ln == 0) {
          unsigned int qk = __builtin_amdgcn_cvt_pk_fp8_f32(u2[0], u2[1], 0u, false);
          qk = __builtin_amdgcn_cvt_pk_fp8_f32(u2[2], u2[3], qk, true);
          unsigned char* wq = U8 + 32 * 2084 + t0 + 4 * g + 33;
          wq[0] = (unsigned char)(qk & 0xFFu);
          wq[1] = (unsigned char)((qk >> 8) & 0xFFu);
          wq[2] = (unsigned char)((qk >> 16) & 0xFFu);
          wq[3] = (unsigned char)(qk >> 24);
        }
      }
    }
  }
  __syncthreads();

  // ---- Phase 2 (pipelined): j in [w*512, (w+1)*512), 8 iters of 64 ----
  f32x4 acc00 = fz, acc01 = fz, acc10 = fz, acc11 = fz;
  f32x4 accl0 = fz, accl1 = fz;
  const bf16x8 ones = mk8(0x3F803F80u, 0x3F803F80u, 0x3F803F80u, 0x3F803F80u);

  const unsigned short* kp = Kp + (size_t)(w * 512 + ln) * 32 + g * 8;
  bf16x8 kf[4];
  #pragma unroll
  for (int q = 0; q < 4; ++q) kf[q] = *(const bf16x8*)(kp + q * 512);

  const unsigned short* vpb = Vp + (size_t)ln * 2048 + w * 512 + 8 * g;
  bf16x8 vf00 = *(const bf16x8*)vpb;
  bf16x8 vf01 = *(const bf16x8*)(vpb + 32);
  bf16x8 vf10 = *(const bf16x8*)(vpb + 16 * 2048);
  bf16x8 vf11 = *(const bf16x8*)(vpb + 16 * 2048 + 32);

  float pv0[16], pv1[16];
  // prologue gather (it = 0), immediate
  {
    const int jc = w * 512;
    const int jcg = jc + 4 * g;
    const int cb = jcg - i0;
    if (jc > i0 + 31) {
      const unsigned char* b0 = U8 + (ln + 1) * 2084 + cb;
      const unsigned char* b1 = U8 + (ln + 17) * 2084 + cb;
      #pragma unroll
      for (int q = 0; q < 4; ++q) {
        const int d0 = *(const int*)(b0 + 16 * q);
        const f32x2 l0 = __builtin_amdgcn_cvt_pk_f32_fp8(d0, false);
        const f32x2 h0 = __builtin_amdgcn_cvt_pk_f32_fp8(d0, true);
        pv0[4 * q + 0] = l0[0]; pv0[4 * q + 1] = l0[1];
        pv0[4 * q + 2] = h0[0]; pv0[4 * q + 3] = h0[1];
        const int d1 = *(const int*)(b1 + 16 * q);
        const f32x2 l1 = __builtin_amdgcn_cvt_pk_f32_fp8(d1, false);
        const f32x2 h1 = __builtin_amdgcn_cvt_pk_f32_fp8(d1, true);
        pv1[4 * q + 0] = l1[0]; pv1[4 * q + 1] = l1[1];
        pv1[4 * q + 2] = h1[0]; pv1[4 * q + 3] = h1[1];
      }
    } else if (jc + 75 <= i0) {
      const unsigned char* a0 = U8 + ln * 2084 + cb + 2048;
      const unsigned char* a1 = U8 + (ln + 16) * 2084 + cb + 2048;
      #pragma unroll
      for (int q = 0; q < 4; ++q) {
        const int d0 = *(const int*)(a0 + 16 * q);
        const f32x2 l0 = __builtin_amdgcn_cvt_pk_f32_fp8(d0, false);
        const f32x2 h0 = __builtin_amdgcn_cvt_pk_f32_fp8(d0, true);
        pv0[4 * q + 0] = l0[0]; pv0[4 * q + 1] = l0[1];
        pv0[4 * q + 2] = h0[0]; pv0[4 * q + 3] = h0[1];
        const int d1 = *(const int*)(a1 + 16 * q);
        const f32x2 l1 = __builtin_amdgcn_cvt_pk_f32_fp8(d1, false);
        const f32x2 h1 = __builtin_amdgcn_cvt_pk_f32_fp8(d1, true);
        pv1[4 * q + 0] = l1[0]; pv1[4 * q + 1] = l1[1];
        pv1[4 * q + 2] = h1[0]; pv1[4 * q + 3] = h1[1];
      }
    } else {
      const int bA0 = ln * 2084 + cb + 2048;
      const int bB0 = (ln + 1) * 2084 + cb;
      const int bA1 = (ln + 16) * 2084 + cb + 2048;
      const int bB1 = (ln + 17) * 2084 + cb;
      const int djg0 = i0 + ln - jcg;
      const int djg1 = i0 + 16 + ln - jcg;
      #pragma unroll
      for (int e = 0; e < 16; ++e) {
        const int co = ((e >> 2) << 4) + (e & 3);
        const unsigned int b0 = U8[(co <= djg0 ? bA0 : bB0) + co];
        pv0[e] = __builtin_amdgcn_cvt_f32_fp8(b0, 0);
        const unsigned int b1 = U8[(co <= djg1 ? bA1 : bB1) + co];
        pv1[e] = __builtin_amdgcn_cvt_f32_fp8(b1, 0);
      }
    }
  }
  // prologue QK^T (it = 0), then advance K to it = 1
  f32x4 st0[4], st1[4];
  __builtin_amdgcn_s_setprio(1);
  #pragma unroll
  for (int q = 0; q < 4; ++q) {
    st0[q] = MFMA16(kf[q], quf0, fz);
    st1[q] = MFMA16(kf[q], quf1, fz);
  }
  __builtin_amdgcn_s_setprio(0);
  kp += 64 * 32;
  #pragma unroll
  for (int q = 0; q < 4; ++q) kf[q] = *(const bf16x8*)(kp + q * 512);

  #pragma unroll
  for (int it = 0; it < 8; ++it) {
    // (1) gather issue for it+1 (raw dwords; unpack deferred past PV)
    int raw0[4], raw1[4];
    bool useraw = false;
    float npv0[16], npv1[16];
    if (it < 7) {
      const int jc2 = w * 512 + (it + 1) * 64;
      const int jcg2 = jc2 + 4 * g;
      const int cb2 = jcg2 - i0;
      if (jc2 > i0 + 31) {
        const unsigned char* b0 = U8 + (ln + 1) * 2084 + cb2;
        const unsigned char* b1 = U8 + (ln + 17) * 2084 + cb2;
        #pragma unroll
        for (int q = 0; q < 4; ++q) {
          raw0[q] = *(const int*)(b0 + 16 * q);
          raw1[q] = *(const int*)(b1 + 16 * q);
        }
        useraw = true;
      } else if (jc2 + 75 <= i0) {
        const unsigned char* a0 = U8 + ln * 2084 + cb2 + 2048;
        const unsigned char* a1 = U8 + (ln + 16) * 2084 + cb2 + 2048;
        #pragma unroll
        for (int q = 0; q < 4; ++q) {
          raw0[q] = *(const int*)(a0 + 16 * q);
          raw1[q] = *(const int*)(a1 + 16 * q);
        }
        useraw = true;
      } else {                       // mixed (<=2 iters/wave): immediate
        const int bA0 = ln * 2084 + cb2 + 2048;
        const int bB0 = (ln + 1) * 2084 + cb2;
        const int bA1 = (ln + 16) * 2084 + cb2 + 2048;
        const int bB1 = (ln + 17) * 2084 + cb2;
        const int djg0 = i0 + ln - jcg2;
        const int djg1 = i0 + 16 + ln - jcg2;
        #pragma unroll
        for (int e = 0; e < 16; ++e) {
          const int co = ((e >> 2) << 4) + (e & 3);
          const unsigned int b0v = U8[(co <= djg0 ? bA0 : bB0) + co];
          npv0[e] = __builtin_amdgcn_cvt_f32_fp8(b0v, 0);
          const unsigned int b1v = U8[(co <= djg1 ? bA1 : bB1) + co];
          npv1[e] = __builtin_amdgcn_cvt_f32_fp8(b1v, 0);
        }
      }
    }

    // (2) QK^T for it+1 from prefetched K; advance K to it+2
    f32x4 nst0[4], nst1[4];
    if (it < 7) {
      __builtin_amdgcn_s_setprio(1);
      #pragma unroll
      for (int q = 0; q < 4; ++q) {
        nst0[q] = MFMA16(kf[q], quf0, fz);
        nst1[q] = MFMA16(kf[q], quf1, fz);
      }
      __builtin_amdgcn_s_setprio(0);
      if (it < 6) {
        kp += 64 * 32;
        #pragma unroll
        for (int q = 0; q < 4; ++q) kf[q] = *(const bf16x8*)(kp + q * 512);
      }
    }

    // (3) exp + pack for current iter (all register-resident)
    float p0[16], p1[16];
    #pragma unroll
    for (int e = 0; e < 16; ++e) {
      p0[e] = exp2fast(st0[e >> 2][e & 3] + pv0[e]);
      p1[e] = exp2fast(st1[e >> 2][e & 3] + pv1[e]);
    }
    const bf16x8 pfr00 = mk8(cvtpk(p0[0], p0[1]), cvtpk(p0[2], p0[3]),
                             cvtpk(p0[4], p0[5]), cvtpk(p0[6], p0[7]));
    const bf16x8 pfr01 = mk8(cvtpk(p0[8], p0[9]), cvtpk(p0[10], p0[11]),
                             cvtpk(p0[12], p0[13]), cvtpk(p0[14], p0[15]));
    const bf16x8 pfr10 = mk8(cvtpk(p1[0], p1[1]), cvtpk(p1[2], p1[3]),
                             cvtpk(p1[4], p1[5]), cvtpk(p1[6], p1[7]));
    const bf16x8 pfr11 = mk8(cvtpk(p1[8], p1[9]), cvtpk(p1[10], p1[11]),
                             cvtpk(p1[12], p1[13]), cvtpk(p1[14], p1[15]));

    // (4) PV + sum MFMAs; then V advance for it+1
    __builtin_amdgcn_s_setprio(1);
    acc00 = MFMA16(vf00, pfr00, acc00);   // group0, d-block 0
    acc00 = MFMA16(vf01, pfr01, acc00);
    acc01 = MFMA16(vf10, pfr00, acc01);   // group0, d-block 1
    acc01 = MFMA16(vf11, pfr01, acc01);
    acc10 = MFMA16(vf00, pfr10, acc10);   // group1, d-block 0
    acc10 = MFMA16(vf01, pfr11, acc10);
    acc11 = MFMA16(vf10, pfr10, acc11);   // group1, d-block 1
    acc11 = MFMA16(vf11, pfr11, acc11);
    accl0 = MFMA16(ones, pfr00, accl0);   // sum of p, group0
    accl0 = MFMA16(ones, pfr01, accl0);
    accl1 = MFMA16(ones, pfr10, accl1);   // sum of p, group1
    accl1 = MFMA16(ones, pfr11, accl1);
    __builtin_amdgcn_s_setprio(0);
    if (it < 7) {
      vpb += 64;
      vf00 = *(const bf16x8*)vpb;
      vf01 = *(const bf16x8*)(vpb + 32);
      vf10 = *(const bf16x8*)(vpb + 16 * 2048);
      vf11 = *(const bf16x8*)(vpb + 16 * 2048 + 32);
    }

    // (5) deferred unpack of raw gather; (6) rotate
    if (it < 7) {
      if (useraw) {
        #pragma unroll
        for (int q = 0; q < 4; ++q) {
          const f32x2 l0 = __builtin_amdgcn_cvt_pk_f32_fp8(raw0[q], false);
          const f32x2 h0 = __builtin_amdgcn_cvt_pk_f32_fp8(raw0[q], true);
          npv0[4 * q + 0] = l0[0]; npv0[4 * q + 1] = l0[1];
          npv0[4 * q + 2] = h0[0]; npv0[4 * q + 3] = h0[1];
          const f32x2 l1 = __builtin_amdgcn_cvt_pk_f32_fp8(raw1[q], false);
          const f32x2 h1 = __builtin_amdgcn_cvt_pk_f32_fp8(raw1[q], true);
          npv1[4 * q + 0] = l1[0]; npv1[4 * q + 1] = l1[1];
          npv1[4 * q + 2] = h1[0]; npv1[4 * q + 3] = h1[1];
        }
      }
      #pragma unroll
      for (int q = 0; q < 4; ++q) { st0[q] = nst0[q]; st1[q] = nst1[q]; }
      #pragma unroll
      for (int e = 0; e < 16; ++e) { pv0[e] = npv0[e]; pv1[e] = npv1[e]; }
    }
  }

  // ---- two-pass cross-wave combine (m=0: plain sums) ----
  if (lane < 16) { slx[w][lane] = accl0[0]; slx[w][lane + 16] = accl1[0]; }
  #pragma unroll
  for (int r = 0; r < 4; ++r) {
    sacc[w][4 * g + r][ln] = acc00[r];
    sacc[w][4 * g + r][ln + 16] = acc10[r];
  }
  __syncthreads();

  for (int pp = tid; pp < 512; pp += 256) {   // pass 1: d 0..15
    const int d = pp >> 5, ii = pp & 31;
    const float Lt = (slx[0][ii] + slx[1][ii]) + (slx[2][ii] + slx[3][ii]);
    const float val = (sacc[0][d][ii] + sacc[1][d][ii]) +
                      (sacc[2][d][ii] + sacc[3][d][ii]);
    CTX[((size_t)(b * 2048 + i0 + ii)) * 512 + h * 32 + d] = f2bf(val / Lt);
  }
  __syncthreads();
  #pragma unroll
  for (int r = 0; r < 4; ++r) {
    sacc[w][4 * g + r][ln] = acc01[r];
    sacc[w][4 * g + r][ln + 16] = acc11[r];
  }
  __syncthreads();
  for (int pp = tid; pp < 512; pp += 256) {   // pass 2: d 16..31
    const int d = pp >> 5, ii = pp & 31;
    const float Lt = (slx[0][ii] + slx[1][ii]) + (slx[2][ii] + slx[3][ii]);
    const float val = (sacc[0][d][ii] + sacc[1][d][ii]) +
                      (sacc[2][d][ii] + sacc[3][d][ii]);
    CTX[((size_t)(b * 2048 + i0 + ii)) * 512 + h * 32 + 16 + d] = f2bf(val / Lt);
  }
}

// ---------------------------------------------------------------------------
// Output GEMM: out = CTX(bf16) @ Wo^T + bo, fp32 out. Tile 128x64.
// ---------------------------------------------------------------------------
__global__ __launch_bounds__(256) void out_gemm(
    const unsigned short* __restrict__ A, const float* __restrict__ W,
    const float* __restrict__ bias, float* __restrict__ out)
{
  __shared__ __align__(16) unsigned short As[128][40];
  __shared__ __align__(16) unsigned short Bs[64][40];
  const int i0 = blockIdx.x * 128;
  const int o0 = blockIdx.y * 64;
  const int tid = threadIdx.x;
  const int w = tid >> 6, lane = tid & 63, g = lane >> 4, ln = lane & 15;

  f32x4 acc[2][4];
  #pragma unroll
  for (int rf = 0; rf < 2; ++rf)
    #pragma unroll
    for (int n = 0; n < 4; ++n) acc[rf][n] = (f32x4){0.f, 0.f, 0.f, 0.f};

  const int srow = tid >> 2;
  const int scol = (tid & 3) * 8;

  for (int k0 = 0; k0 < 512; k0 += 32) {
    if (k0) __syncthreads();
    *(bf16x8*)&As[srow][scol] =
        *(const bf16x8*)(A + (size_t)(i0 + srow) * 512 + k0 + scol);
    *(bf16x8*)&As[64 + srow][scol] =
        *(const bf16x8*)(A + (size_t)(i0 + 64 + srow) * 512 + k0 + scol);
    {
      const float* sb = W + (size_t)(o0 + srow) * 512 + k0 + scol;
      f32x4 b0 = *(const f32x4*)sb;
      f32x4 b1 = *(const f32x4*)(sb + 4);
      uint4 bv2;
      bv2.x = cvtpk(b0[0], b0[1]); bv2.y = cvtpk(b0[2], b0[3]);
      bv2.z = cvtpk(b1[0], b1[1]); bv2.w = cvtpk(b1[2], b1[3]);
      *(uint4*)&Bs[srow][scol] = bv2;
    }
    __syncthreads();
    const bf16x8 af0 = *(const bf16x8*)&As[w * 32 + ln][g * 8];
    const bf16x8 af1 = *(const bf16x8*)&As[w * 32 + 16 + ln][g * 8];
    #pragma unroll
    for (int n = 0; n < 4; ++n) {
      const bf16x8 bfv = *(const bf16x8*)&Bs[n * 16 + ln][g * 8];
      acc[0][n] = MFMA16(af0, bfv, acc[0][n]);
      acc[1][n] = MFMA16(af1, bfv, acc[1][n]);
    }
  }

  #pragma unroll
  for (int rf = 0; rf < 2; ++rf) {
    #pragma unroll
    for (int n = 0; n < 4; ++n) {
      const int o = o0 + n * 16 + ln;
      const float bval = bias[o];
      #pragma unroll
      for (int r = 0; r < 4; ++r) {
        const int i = i0 + w * 32 + rf * 16 + 4 * g + r;
        out[(size_t)i * 512 + o] = acc[rf][n][r] + bval;
      }
    }
  }
}

extern "C" void kernel_launch(void* const* d_in, const int* in_sizes, int n_in,
                              void* d_out, int out_size, void* d_ws, size_t ws_size,
                              hipStream_t stream) {
  const float* query = (const float*)d_in[0];
  const float* key_  = (const float*)d_in[1];
  const float* value = (const float*)d_in[2];
  const float* pos   = (const float*)d_in[3];
  const float* Wq = (const float*)d_in[4];
  const float* bq = (const float*)d_in[5];
  const float* Wk = (const float*)d_in[6];
  const float* bk = (const float*)d_in[7];
  const float* Wv = (const float*)d_in[8];
  const float* bv = (const float*)d_in[9];
  const float* Wp = (const float*)d_in[10];
  const float* ub = (const float*)d_in[11];
  const float* vbias = (const float*)d_in[12];
  const float* Wo = (const float*)d_in[13];
  const float* bo = (const float*)d_in[14];

  char* ws = (char*)d_ws;
  unsigned short* QU  = (unsigned short*)(ws);
  unsigned short* QV  = (unsigned short*)(ws + 4194304);
  unsigned short* Kb  = (unsigned short*)(ws + 2 * 4194304);
  unsigned short* Vs  = (unsigned short*)(ws + 3 * 4194304);
  unsigned short* Pb  = (unsigned short*)(ws + 4 * 4194304);
  unsigned short* CTX = (unsigned short*)(ws + 4 * 4194304 + 2097152);

  proj_fused<<<dim3(32, 8, 4), dim3(256), 0, stream>>>(
      query, key_, value, pos, Wq, Wk, Wv, Wp, bq, bk, bv, ub, vbias,
      QU, QV, Kb, Vs, Pb);
  attn_kernel<<<dim3(64, 32), dim3(256), 0, stream>>>(QU, QV, Kb, Vs, Pb, CTX);
  out_gemm<<<dim3(32, 8), dim3(256), 0, stream>>>(CTX, Wo, bo, (float*)d_out);
}

// Round 19
// 128.457 us; speedup vs baseline: 1.2676x; 1.0201x over previous
//
#include <hip/hip_runtime.h>

typedef __attribute__((ext_vector_type(8))) short bf16x8;
typedef __attribute__((ext_vector_type(4))) float f32x4;
typedef __attribute__((ext_vector_type(2))) float f32x2;

#define MFMA16(a, b, c) __builtin_amdgcn_mfma_f32_16x16x32_bf16(a, b, c, 0, 0, 0)

__device__ __forceinline__ unsigned int cvtpk(float lo, float hi) {
  unsigned int r;
  asm("v_cvt_pk_bf16_f32 %0, %1, %2" : "=v"(r) : "v"(lo), "v"(hi));
  return r;
}
__device__ __forceinline__ float exp2fast(float x) {
  float r;
  asm("v_exp_f32 %0, %1" : "=v"(r) : "v"(x));
  return r;
}
__device__ __forceinline__ unsigned short f2bf(float f) {
  union { float f; unsigned int u; } x; x.f = f;
  unsigned int u = x.u;
  return (unsigned short)((u + 0x7FFFu + ((u >> 16) & 1u)) >> 16);
}
__device__ __forceinline__ bf16x8 mk8(unsigned int w0, unsigned int w1,
                                      unsigned int w2, unsigned int w3) {
  union { unsigned int w[4]; bf16x8 v; } u;
  u.w[0] = w0; u.w[1] = w1; u.w[2] = w2; u.w[3] = w3;
  return u.v;
}

// log2(e)/sqrt(512): folds softmax scale AND exp->exp2 conversion into Q.
#define CSCALE 0.0637669439631016f

// ---------------------------------------------------------------------------
// Fused projection GEMMs: Y = X @ W^T + bias, tile 128x64, DOUBLE-BUFFERED
// LDS staging (reg-stage next K-tile before the MFMAs; one barrier/K-step).
// blockIdx.z selects mode:
//  0: QU = (Y+u_bias)*CSCALE, QV = (Y+v_bias)*CSCALE, layout [b*16+h][l][32]
//  1: K,  layout [b*16+h][l][32]
//  2: V sigma-permuted transposed [b*16+h][32][l'] (l' permuted per 32-block)
//  3: P,  layout [h][t][32]  (M=2048, only blockIdx.x<16 active)
// ---------------------------------------------------------------------------
__global__ __launch_bounds__(256) void proj_fused(
    const float* __restrict__ Xq, const float* __restrict__ Xk,
    const float* __restrict__ Xv, const float* __restrict__ Xp,
    const float* __restrict__ Wq, const float* __restrict__ Wk,
    const float* __restrict__ Wv, const float* __restrict__ Wp,
    const float* __restrict__ bq, const float* __restrict__ bk,
    const float* __restrict__ bv,
    const float* __restrict__ ub, const float* __restrict__ vb,
    unsigned short* __restrict__ QU, unsigned short* __restrict__ QV,
    unsigned short* __restrict__ Kb, unsigned short* __restrict__ Vs,
    unsigned short* __restrict__ Pb)
{
  const int mode = blockIdx.z;
  if (mode == 3 && blockIdx.x >= 16) return;
  const float* X = (mode == 0) ? Xq : (mode == 1) ? Xk : (mode == 2) ? Xv : Xp;
  const float* W = (mode == 0) ? Wq : (mode == 1) ? Wk : (mode == 2) ? Wv : Wp;
  const float* bias = (mode == 0) ? bq : (mode == 1) ? bk : (mode == 2) ? bv : nullptr;

  __shared__ __align__(16) unsigned short As[2][128][40];
  __shared__ __align__(16) unsigned short Bs[2][64][40];
  const int i0 = blockIdx.x * 128;
  const int o0 = blockIdx.y * 64;
  const int tid = threadIdx.x;
  const int w = tid >> 6, lane = tid & 63, g = lane >> 4, ln = lane & 15;

  f32x4 acc[2][4];
  #pragma unroll
  for (int rf = 0; rf < 2; ++rf)
    #pragma unroll
    for (int n = 0; n < 4; ++n) acc[rf][n] = (f32x4){0.f, 0.f, 0.f, 0.f};

  const int srow = tid >> 2;          // 0..63
  const int scol = (tid & 3) * 8;
  const float* Xr0 = X + (size_t)(i0 + srow) * 512 + scol;
  const float* Xr1 = X + (size_t)(i0 + 64 + srow) * 512 + scol;
  const float* Wr  = W + (size_t)(o0 + srow) * 512 + scol;

  // prologue: stage k-tile 0 into buffer 0
  {
    f32x4 a0 = *(const f32x4*)Xr0;
    f32x4 a1 = *(const f32x4*)(Xr0 + 4);
    f32x4 a2 = *(const f32x4*)Xr1;
    f32x4 a3 = *(const f32x4*)(Xr1 + 4);
    f32x4 b0 = *(const f32x4*)Wr;
    f32x4 b1 = *(const f32x4*)(Wr + 4);
    uint4 av; av.x = cvtpk(a0[0], a0[1]); av.y = cvtpk(a0[2], a0[3]);
    av.z = cvtpk(a1[0], a1[1]); av.w = cvtpk(a1[2], a1[3]);
    *(uint4*)&As[0][srow][scol] = av;
    uint4 av2; av2.x = cvtpk(a2[0], a2[1]); av2.y = cvtpk(a2[2], a2[3]);
    av2.z = cvtpk(a3[0], a3[1]); av2.w = cvtpk(a3[2], a3[3]);
    *(uint4*)&As[0][64 + srow][scol] = av2;
    uint4 bv2; bv2.x = cvtpk(b0[0], b0[1]); bv2.y = cvtpk(b0[2], b0[3]);
    bv2.z = cvtpk(b1[0], b1[1]); bv2.w = cvtpk(b1[2], b1[3]);
    *(uint4*)&Bs[0][srow][scol] = bv2;
  }
  __syncthreads();

  for (int kk = 0; kk < 16; ++kk) {
    const int cur = kk & 1;
    f32x4 na0, na1, na2, na3, nb0, nb1;
    if (kk < 15) {                     // issue next tile's loads first
      const int k0 = (kk + 1) * 32;
      na0 = *(const f32x4*)(Xr0 + k0);
      na1 = *(const f32x4*)(Xr0 + k0 + 4);
      na2 = *(const f32x4*)(Xr1 + k0);
      na3 = *(const f32x4*)(Xr1 + k0 + 4);
      nb0 = *(const f32x4*)(Wr + k0);
      nb1 = *(const f32x4*)(Wr + k0 + 4);
    }
    const bf16x8 af0 = *(const bf16x8*)&As[cur][w * 32 + ln][g * 8];
    const bf16x8 af1 = *(const bf16x8*)&As[cur][w * 32 + 16 + ln][g * 8];
    #pragma unroll
    for (int n = 0; n < 4; ++n) {
      const bf16x8 bfv = *(const bf16x8*)&Bs[cur][n * 16 + ln][g * 8];
      acc[0][n] = MFMA16(af0, bfv, acc[0][n]);
      acc[1][n] = MFMA16(af1, bfv, acc[1][n]);
    }
    if (kk < 15) {
      const int nxt = cur ^ 1;
      uint4 av; av.x = cvtpk(na0[0], na0[1]); av.y = cvtpk(na0[2], na0[3]);
      av.z = cvtpk(na1[0], na1[1]); av.w = cvtpk(na1[2], na1[3]);
      *(uint4*)&As[nxt][srow][scol] = av;
      uint4 av2; av2.x = cvtpk(na2[0], na2[1]); av2.y = cvtpk(na2[2], na2[3]);
      av2.z = cvtpk(na3[0], na3[1]); av2.w = cvtpk(na3[2], na3[3]);
      *(uint4*)&As[nxt][64 + srow][scol] = av2;
      uint4 bv2; bv2.x = cvtpk(nb0[0], nb0[1]); bv2.y = cvtpk(nb0[2], nb0[3]);
      bv2.z = cvtpk(nb1[0], nb1[1]); bv2.w = cvtpk(nb1[2], nb1[3]);
      *(uint4*)&Bs[nxt][srow][scol] = bv2;
      __syncthreads();
    }
  }

  #pragma unroll
  for (int rf = 0; rf < 2; ++rf) {
    #pragma unroll
    for (int n = 0; n < 4; ++n) {
      const int o = o0 + n * 16 + ln;
      const float bval = bias ? bias[o] : 0.f;
      const int h = o >> 5, d = o & 31;
      #pragma unroll
      for (int r = 0; r < 4; ++r) {
        const int i = i0 + w * 32 + rf * 16 + 4 * g + r;
        const float y = acc[rf][n][r] + bval;
        if (mode == 0) {
          const int b = i >> 11, li = i & 2047;
          const size_t a = (((size_t)(b * 16 + h)) * 2048 + li) * 32 + d;
          QU[a] = f2bf(CSCALE * (y + ub[o]));
          QV[a] = f2bf(CSCALE * (y + vb[o]));
        } else if (mode == 1) {
          const int b = i >> 11, li = i & 2047;
          const size_t a = (((size_t)(b * 16 + h)) * 2048 + li) * 32 + d;
          Kb[a] = f2bf(y);
        } else if (mode == 2) {
          const int b = i >> 11, li = i & 2047;
          const int blk = li >> 5, bb = li & 31;
          const int k = (bb < 16) ? (((bb >> 2) << 3) + (bb & 3))
                                  : ((((bb - 16) >> 2) << 3) + 4 + ((bb - 16) & 3));
          const size_t a = (((size_t)(b * 16 + h)) * 32 + d) * 2048 + (blk << 5) + k;
          Vs[a] = f2bf(y);
        } else {
          Pb[((size_t)h * 2048 + i) * 32 + d] = f2bf(y);
        }
      }
    }
  }
}

// ---------------------------------------------------------------------------
// Fused relative attention (R18-passing kernel, byte-exact).
// One WG = (b, h, 32 query rows), 4 waves. Phase 2 software-pipelined.
// ---------------------------------------------------------------------------
__global__ __launch_bounds__(256, 2) void attn_kernel(
    const unsigned short* __restrict__ QU, const unsigned short* __restrict__ QV,
    const unsigned short* __restrict__ Kb, const unsigned short* __restrict__ Vs,
    const unsigned short* __restrict__ Pb, unsigned short* __restrict__ CTX)
{
  __shared__ __align__(16) unsigned char U8[33 * 2084];  // 68772 B
  __shared__ __align__(16) float sacc[4][16][32];        // 8192 B
  __shared__ float slx[4][32];                           // 512 B

  // XCD-aware bijective swizzle: 2048 WGs, 256 slots/XCD, 4 bh per XCD.
  const int n = blockIdx.y * 64 + blockIdx.x;
  const int xcd = n & 7, slot = n >> 3;
  const int bh = (xcd << 2) | (slot >> 6);
  const int i0 = (slot & 63) * 32;
  const int h = bh & 15;
  const int b = bh >> 4;
  const int tid = threadIdx.x;
  const int w = tid >> 6, lane = tid & 63, g = lane >> 4, ln = lane & 15;

  const unsigned short* QUp = QU + (size_t)bh * 65536;
  const unsigned short* QVp = QV + (size_t)bh * 65536;
  const unsigned short* Kp  = Kb + (size_t)bh * 65536;
  const unsigned short* Vp  = Vs + (size_t)bh * 65536;
  const unsigned short* Pp  = Pb + (size_t)h * 65536;

  const f32x4 fz = (f32x4){0.f, 0.f, 0.f, 0.f};

  const bf16x8 quf0 = *(const bf16x8*)(QUp + (size_t)(i0 + ln) * 32 + g * 8);
  const bf16x8 quf1 = *(const bf16x8*)(QUp + (size_t)(i0 + 16 + ln) * 32 + g * 8);
  const bf16x8 qvf0 = *(const bf16x8*)(QVp + (size_t)(i0 + ln) * 32 + g * 8);
  const bf16x8 qvf1 = *(const bf16x8*)(QVp + (size_t)(i0 + 16 + ln) * 32 + g * 8);
  const int r32 = (i0 + 32 < 2048) ? (i0 + 32) : 2047;  // last tile: never read
  const bf16x8 qv32 = *(const bf16x8*)(QVp + (size_t)r32 * 32 + g * 8);

  // zero sentinels: row r, byte col r == (t=-1) for rows 1..32
  if (tid < 32) U8[(tid + 1) * 2084 + (tid + 1)] = 0;

  // ---- Phase 1: build U (fp8, diagonal), rows {ln, ln+16, 32}, P ring 4 ----
  const unsigned short* Pb0 = Pp + (size_t)(w * 16 + ln) * 32 + g * 8;
  bf16x8 pfb0 = *(const bf16x8*)(Pb0);
  bf16x8 pfb1 = *(const bf16x8*)(Pb0 + 64 * 32);
  bf16x8 pfb2 = *(const bf16x8*)(Pb0 + 128 * 32);
  bf16x8 pfb3 = *(const bf16x8*)(Pb0 + 192 * 32);
  const int wr0 = ln * 2084 + 4 * g + ln + 1;          // group0 byte base (+t0)
  const int wr1 = (ln + 16) * 2084 + 4 * g + ln + 17;  // group1 byte base (+t0)
  for (int itb = 0; itb < 8; ++itb) {
    #pragma unroll
    for (int k = 0; k < 4; ++k) {
      const int itt = itb * 4 + k;
      const int t0 = itt * 64 + w * 16;
      bf16x8 cur;
      if (k == 0) cur = pfb0; else if (k == 1) cur = pfb1;
      else if (k == 2) cur = pfb2; else cur = pfb3;
      if (itb < 7) {
        const bf16x8 nx = *(const bf16x8*)(Pb0 + (size_t)((itt + 4) * 64) * 32);
        if (k == 0) pfb0 = nx; else if (k == 1) pfb1 = nx;
        else if (k == 2) pfb2 = nx; else pfb3 = nx;
      }
      {
        f32x4 u0 = MFMA16(cur, qvf0, fz);   // U[ln][t0+4g+r]
        unsigned int pk = __builtin_amdgcn_cvt_pk_fp8_f32(u0[0], u0[1], 0u, false);
        pk = __builtin_amdgcn_cvt_pk_fp8_f32(u0[2], u0[3], pk, true);
        unsigned char* wp = U8 + wr0 + t0;
        wp[0] = (unsigned char)(pk & 0xFFu);
        wp[1] = (unsigned char)((pk >> 8) & 0xFFu);
        wp[2] = (unsigned char)((pk >> 16) & 0xFFu);
        wp[3] = (unsigned char)(pk >> 24);
      }
      {
        f32x4 u1 = MFMA16(cur, qvf1, fz);   // U[ln+16][t0+4g+r]
        unsigned int pk = __builtin_amdgcn_cvt_pk_fp8_f32(u1[0], u1[1], 0u, false);
        pk = __builtin_amdgcn_cvt_pk_fp8_f32(u1[2], u1[3], pk, true);
        unsigned char* wp = U8 + wr1 + t0;
        wp[0] = (unsigned char)(pk & 0xFFu);
        wp[1] = (unsigned char)((pk >> 8) & 0xFFu);
        wp[2] = (unsigned char)((pk >> 16) & 0xFFu);
        wp[3] = (unsigned char)(pk >> 24);
      }
      if (t0 <= 2014 - i0) {            // row 32 only read for t <= 2014-i0
        f32x4 u2 = MFMA16(cur, qv32, fz);
        if (ln == 0) {
          unsigned int qk = __builtin_amdgcn_cvt_pk_fp8_f32(u2[0], u2[1], 0u, false);
          qk = __builtin_amdgcn_cvt_pk_fp8_f32(u2[2], u2[3], qk, true);
          unsigned char* wq = U8 + 32 * 2084 + t0 + 4 * g + 33;
          wq[0] = (unsigned char)(qk & 0xFFu);
          wq[1] = (unsigned char)((qk >> 8) & 0xFFu);
          wq[2] = (unsigned char)((qk >> 16) & 0xFFu);
          wq[3] = (unsigned char)(qk >> 24);
        }
      }
    }
  }
  __syncthreads();

  // ---- Phase 2 (pipelined): j in [w*512, (w+1)*512), 8 iters of 64 ----
  f32x4 acc00 = fz, acc01 = fz, acc10 = fz, acc11 = fz;
  f32x4 accl0 = fz, accl1 = fz;
  const bf16x8 ones = mk8(0x3F803F80u, 0x3F803F80u, 0x3F803F80u, 0x3F803F80u);

  const unsigned short* kp = Kp + (size_t)(w * 512 + ln) * 32 + g * 8;
  bf16x8 kf[4];
  #pragma unroll
  for (int q = 0; q < 4; ++q) kf[q] = *(const bf16x8*)(kp + q * 512);

  const unsigned short* vpb = Vp + (size_t)ln * 2048 + w * 512 + 8 * g;
  bf16x8 vf00 = *(const bf16x8*)vpb;
  bf16x8 vf01 = *(const bf16x8*)(vpb + 32);
  bf16x8 vf10 = *(const bf16x8*)(vpb + 16 * 2048);
  bf16x8 vf11 = *(const bf16x8*)(vpb + 16 * 2048 + 32);

  float pv0[16], pv1[16];
  // prologue gather (it = 0), immediate
  {
    const int jc = w * 512;
    const int jcg = jc + 4 * g;
    const int cb = jcg - i0;
    if (jc > i0 + 31) {
      const unsigned char* b0 = U8 + (ln + 1) * 2084 + cb;
      const unsigned char* b1 = U8 + (ln + 17) * 2084 + cb;
      #pragma unroll
      for (int q = 0; q < 4; ++q) {
        const int d0 = *(const int*)(b0 + 16 * q);
        const f32x2 l0 = __builtin_amdgcn_cvt_pk_f32_fp8(d0, false);
        const f32x2 h0 = __builtin_amdgcn_cvt_pk_f32_fp8(d0, true);
        pv0[4 * q + 0] = l0[0]; pv0[4 * q + 1] = l0[1];
        pv0[4 * q + 2] = h0[0]; pv0[4 * q + 3] = h0[1];
        const int d1 = *(const int*)(b1 + 16 * q);
        const f32x2 l1 = __builtin_amdgcn_cvt_pk_f32_fp8(d1, false);
        const f32x2 h1 = __builtin_amdgcn_cvt_pk_f32_fp8(d1, true);
        pv1[4 * q + 0] = l1[0]; pv1[4 * q + 1] = l1[1];
        pv1[4 * q + 2] = h1[0]; pv1[4 * q + 3] = h1[1];
      }
    } else if (jc + 75 <= i0) {
      const unsigned char* a0 = U8 + ln * 2084 + cb + 2048;
      const unsigned char* a1 = U8 + (ln + 16) * 2084 + cb + 2048;
      #pragma unroll
      for (int q = 0; q < 4; ++q) {
        const int d0 = *(const int*)(a0 + 16 * q);
        const f32x2 l0 = __builtin_amdgcn_cvt_pk_f32_fp8(d0, false);
        const f32x2 h0 = __builtin_amdgcn_cvt_pk_f32_fp8(d0, true);
        pv0[4 * q + 0] = l0[0]; pv0[4 * q + 1] = l0[1];
        pv0[4 * q + 2] = h0[0]; pv0[4 * q + 3] = h0[1];
        const int d1 = *(const int*)(a1 + 16 * q);
        const f32x2 l1 = __builtin_amdgcn_cvt_pk_f32_fp8(d1, false);
        const f32x2 h1 = __builtin_amdgcn_cvt_pk_f32_fp8(d1, true);
        pv1[4 * q + 0] = l1[0]; pv1[4 * q + 1] = l1[1];
        pv1[4 * q + 2] = h1[0]; pv1[4 * q + 3] = h1[1];
      }
    } else {
      const int bA0 = ln * 2084 + cb + 2048;
      const int bB0 = (ln + 1) * 2084 + cb;
      const int bA1 = (ln + 16) * 2084 + cb + 2048;
      const int bB1 = (ln + 17) * 2084 + cb;
      const int djg0 = i0 + ln - jcg;
      const int djg1 = i0 + 16 + ln - jcg;
      #pragma unroll
      for (int e = 0; e < 16; ++e) {
        const int co = ((e >> 2) << 4) + (e & 3);
        const unsigned int b0 = U8[(co <= djg0 ? bA0 : bB0) + co];
        pv0[e] = __builtin_amdgcn_cvt_f32_fp8(b0, 0);
        const unsigned int b1 = U8[(co <= djg1 ? bA1 : bB1) + co];
        pv1[e] = __builtin_amdgcn_cvt_f32_fp8(b1, 0);
      }
    }
  }
  // prologue QK^T (it = 0), then advance K to it = 1
  f32x4 st0[4], st1[4];
  __builtin_amdgcn_s_setprio(1);
  #pragma unroll
  for (int q = 0; q < 4; ++q) {
    st0[q] = MFMA16(kf[q], quf0, fz);
    st1[q] = MFMA16(kf[q], quf1, fz);
  }
  __builtin_amdgcn_s_setprio(0);
  kp += 64 * 32;
  #pragma unroll
  for (int q = 0; q < 4; ++q) kf[q] = *(const bf16x8*)(kp + q * 512);

  #pragma unroll
  for (int it = 0; it < 8; ++it) {
    // (1) gather issue for it+1 (raw dwords; unpack deferred past PV)
    int raw0[4], raw1[4];
    bool useraw = false;
    float npv0[16], npv1[16];
    if (it < 7) {
      const int jc2 = w * 512 + (it + 1) * 64;
      const int jcg2 = jc2 + 4 * g;
      const int cb2 = jcg2 - i0;
      if (jc2 > i0 + 31) {
        const unsigned char* b0 = U8 + (ln + 1) * 2084 + cb2;
        const unsigned char* b1 = U8 + (ln + 17) * 2084 + cb2;
        #pragma unroll
        for (int q = 0; q < 4; ++q) {
          raw0[q] = *(const int*)(b0 + 16 * q);
          raw1[q] = *(const int*)(b1 + 16 * q);
        }
        useraw = true;
      } else if (jc2 + 75 <= i0) {
        const unsigned char* a0 = U8 + ln * 2084 + cb2 + 2048;
        const unsigned char* a1 = U8 + (ln + 16) * 2084 + cb2 + 2048;
        #pragma unroll
        for (int q = 0; q < 4; ++q) {
          raw0[q] = *(const int*)(a0 + 16 * q);
          raw1[q] = *(const int*)(a1 + 16 * q);
        }
        useraw = true;
      } else {                       // mixed (<=2 iters/wave): immediate
        const int bA0 = ln * 2084 + cb2 + 2048;
        const int bB0 = (ln + 1) * 2084 + cb2;
        const int bA1 = (ln + 16) * 2084 + cb2 + 2048;
        const int bB1 = (ln + 17) * 2084 + cb2;
        const int djg0 = i0 + ln - jcg2;
        const int djg1 = i0 + 16 + ln - jcg2;
        #pragma unroll
        for (int e = 0; e < 16; ++e) {
          const int co = ((e >> 2) << 4) + (e & 3);
          const unsigned int b0v = U8[(co <= djg0 ? bA0 : bB0) + co];
          npv0[e] = __builtin_amdgcn_cvt_f32_fp8(b0v, 0);
          const unsigned int b1v = U8[(co <= djg1 ? bA1 : bB1) + co];
          npv1[e] = __builtin_amdgcn_cvt_f32_fp8(b1v, 0);
        }
      }
    }

    // (2) QK^T for it+1 from prefetched K; advance K to it+2
    f32x4 nst0[4], nst1[4];
    if (it < 7) {
      __builtin_amdgcn_s_setprio(1);
      #pragma unroll
      for (int q = 0; q < 4; ++q) {
        nst0[q] = MFMA16(kf[q], quf0, fz);
        nst1[q] = MFMA16(kf[q], quf1, fz);
      }
      __builtin_amdgcn_s_setprio(0);
      if (it < 6) {
        kp += 64 * 32;
        #pragma unroll
        for (int q = 0; q < 4; ++q) kf[q] = *(const bf16x8*)(kp + q * 512);
      }
    }

    // (3) exp + pack for current iter (all register-resident)
    float p0[16], p1[16];
    #pragma unroll
    for (int e = 0; e < 16; ++e) {
      p0[e] = exp2fast(st0[e >> 2][e & 3] + pv0[e]);
      p1[e] = exp2fast(st1[e >> 2][e & 3] + pv1[e]);
    }
    const bf16x8 pfr00 = mk8(cvtpk(p0[0], p0[1]), cvtpk(p0[2], p0[3]),
                             cvtpk(p0[4], p0[5]), cvtpk(p0[6], p0[7]));
    const bf16x8 pfr01 = mk8(cvtpk(p0[8], p0[9]), cvtpk(p0[10], p0[11]),
                             cvtpk(p0[12], p0[13]), cvtpk(p0[14], p0[15]));
    const bf16x8 pfr10 = mk8(cvtpk(p1[0], p1[1]), cvtpk(p1[2], p1[3]),
                             cvtpk(p1[4], p1[5]), cvtpk(p1[6], p1[7]));
    const bf16x8 pfr11 = mk8(cvtpk(p1[8], p1[9]), cvtpk(p1[10], p1[11]),
                             cvtpk(p1[12], p1[13]), cvtpk(p1[14], p1[15]));

    // (4) PV + sum MFMAs; then V advance for it+1
    __builtin_amdgcn_s_setprio(1);
    acc00 = MFMA16(vf00, pfr00, acc00);   // group0, d-block 0
    acc00 = MFMA16(vf01, pfr01, acc00);
    acc01 = MFMA16(vf10, pfr00, acc01);   // group0, d-block 1
    acc01 = MFMA16(vf11, pfr01, acc01);
    acc10 = MFMA16(vf00, pfr10, acc10);   // group1, d-block 0
    acc10 = MFMA16(vf01, pfr11, acc10);
    acc11 = MFMA16(vf10, pfr10, acc11);   // group1, d-block 1
    acc11 = MFMA16(vf11, pfr11, acc11);
    accl0 = MFMA16(ones, pfr00, accl0);   // sum of p, group0
    accl0 = MFMA16(ones, pfr01, accl0);
    accl1 = MFMA16(ones, pfr10, accl1);   // sum of p, group1
    accl1 = MFMA16(ones, pfr11, accl1);
    __builtin_amdgcn_s_setprio(0);
    if (it < 7) {
      vpb += 64;
      vf00 = *(const bf16x8*)vpb;
      vf01 = *(const bf16x8*)(vpb + 32);
      vf10 = *(const bf16x8*)(vpb + 16 * 2048);
      vf11 = *(const bf16x8*)(vpb + 16 * 2048 + 32);
    }

    // (5) deferred unpack of raw gather; (6) rotate
    if (it < 7) {
      if (useraw) {
        #pragma unroll
        for (int q = 0; q < 4; ++q) {
          const f32x2 l0 = __builtin_amdgcn_cvt_pk_f32_fp8(raw0[q], false);
          const f32x2 h0 = __builtin_amdgcn_cvt_pk_f32_fp8(raw0[q], true);
          npv0[4 * q + 0] = l0[0]; npv0[4 * q + 1] = l0[1];
          npv0[4 * q + 2] = h0[0]; npv0[4 * q + 3] = h0[1];
          const f32x2 l1 = __builtin_amdgcn_cvt_pk_f32_fp8(raw1[q], false);
          const f32x2 h1 = __builtin_amdgcn_cvt_pk_f32_fp8(raw1[q], true);
          npv1[4 * q + 0] = l1[0]; npv1[4 * q + 1] = l1[1];
          npv1[4 * q + 2] = h1[0]; npv1[4 * q + 3] = h1[1];
        }
      }
      #pragma unroll
      for (int q = 0; q < 4; ++q) { st0[q] = nst0[q]; st1[q] = nst1[q]; }
      #pragma unroll
      for (int e = 0; e < 16; ++e) { pv0[e] = npv0[e]; pv1[e] = npv1[e]; }
    }
  }

  // ---- two-pass cross-wave combine (m=0: plain sums) ----
  if (lane < 16) { slx[w][lane] = accl0[0]; slx[w][lane + 16] = accl1[0]; }
  #pragma unroll
  for (int r = 0; r < 4; ++r) {
    sacc[w][4 * g + r][ln] = acc00[r];
    sacc[w][4 * g + r][ln + 16] = acc10[r];
  }
  __syncthreads();

  for (int pp = tid; pp < 512; pp += 256) {   // pass 1: d 0..15
    const int d = pp >> 5, ii = pp & 31;
    const float Lt = (slx[0][ii] + slx[1][ii]) + (slx[2][ii] + slx[3][ii]);
    const float val = (sacc[0][d][ii] + sacc[1][d][ii]) +
                      (sacc[2][d][ii] + sacc[3][d][ii]);
    CTX[((size_t)(b * 2048 + i0 + ii)) * 512 + h * 32 + d] = f2bf(val / Lt);
  }
  __syncthreads();
  #pragma unroll
  for (int r = 0; r < 4; ++r) {
    sacc[w][4 * g + r][ln] = acc01[r];
    sacc[w][4 * g + r][ln + 16] = acc11[r];
  }
  __syncthreads();
  for (int pp = tid; pp < 512; pp += 256) {   // pass 2: d 16..31
    const int d = pp >> 5, ii = pp & 31;
    const float Lt = (slx[0][ii] + slx[1][ii]) + (slx[2][ii] + slx[3][ii]);
    const float val = (sacc[0][d][ii] + sacc[1][d][ii]) +
                      (sacc[2][d][ii] + sacc[3][d][ii]);
    CTX[((size_t)(b * 2048 + i0 + ii)) * 512 + h * 32 + 16 + d] = f2bf(val / Lt);
  }
}

// ---------------------------------------------------------------------------
// Output GEMM: out = CTX(bf16) @ Wo^T + bo, fp32 out. Tile 128x64,
// double-buffered LDS staging, one barrier per K-step.
// ---------------------------------------------------------------------------
__global__ __launch_bounds__(256) void out_gemm(
    const unsigned short* __restrict__ A, const float* __restrict__ W,
    const float* __restrict__ bias, float* __restrict__ out)
{
  __shared__ __align__(16) unsigned short As[2][128][40];
  __shared__ __align__(16) unsigned short Bs[2][64][40];
  const int i0 = blockIdx.x * 128;
  const int o0 = blockIdx.y * 64;
  const int tid = threadIdx.x;
  const int w = tid >> 6, lane = tid & 63, g = lane >> 4, ln = lane & 15;

  f32x4 acc[2][4];
  #pragma unroll
  for (int rf = 0; rf < 2; ++rf)
    #pragma unroll
    for (int n = 0; n < 4; ++n) acc[rf][n] = (f32x4){0.f, 0.f, 0.f, 0.f};

  const int srow = tid >> 2;
  const int scol = (tid & 3) * 8;
  const unsigned short* Ar0 = A + (size_t)(i0 + srow) * 512 + scol;
  const unsigned short* Ar1 = A + (size_t)(i0 + 64 + srow) * 512 + scol;
  const float* Wr = W + (size_t)(o0 + srow) * 512 + scol;

  {
    *(bf16x8*)&As[0][srow][scol] = *(const bf16x8*)Ar0;
    *(bf16x8*)&As[0][64 + srow][scol] = *(const bf16x8*)Ar1;
    f32x4 b0 = *(const f32x4*)Wr;
    f32x4 b1 = *(const f32x4*)(Wr + 4);
    uint4 bv2; bv2.x = cvtpk(b0[0], b0[1]); bv2.y = cvtpk(b0[2], b0[3]);
    bv2.z = cvtpk(b1[0], b1[1]); bv2.w = cvtpk(b1[2], b1[3]);
    *(uint4*)&Bs[0][srow][scol] = bv2;
  }
  __syncthreads();

  for (int kk = 0; kk < 16; ++kk) {
    const int cur = kk & 1;
    bf16x8 nA0, nA1;
    f32x4 nb0, nb1;
    if (kk < 15) {
      const int k0 = (kk + 1) * 32;
      nA0 = *(const bf16x8*)(Ar0 + k0);
      nA1 = *(const bf16x8*)(Ar1 + k0);
      nb0 = *(const f32x4*)(Wr + k0);
      nb1 = *(const f32x4*)(Wr + k0 + 4);
    }
    const bf16x8 af0 = *(const bf16x8*)&As[cur][w * 32 + ln][g * 8];
    const bf16x8 af1 = *(const bf16x8*)&As[cur][w * 32 + 16 + ln][g * 8];
    #pragma unroll
    for (int n = 0; n < 4; ++n) {
      const bf16x8 bfv = *(const bf16x8*)&Bs[cur][n * 16 + ln][g * 8];
      acc[0][n] = MFMA16(af0, bfv, acc[0][n]);
      acc[1][n] = MFMA16(af1, bfv, acc[1][n]);
    }
    if (kk < 15) {
      const int nxt = cur ^ 1;
      *(bf16x8*)&As[nxt][srow][scol] = nA0;
      *(bf16x8*)&As[nxt][64 + srow][scol] = nA1;
      uint4 bv2; bv2.x = cvtpk(nb0[0], nb0[1]); bv2.y = cvtpk(nb0[2], nb0[3]);
      bv2.z = cvtpk(nb1[0], nb1[1]); bv2.w = cvtpk(nb1[2], nb1[3]);
      *(uint4*)&Bs[nxt][srow][scol] = bv2;
      __syncthreads();
    }
  }

  #pragma unroll
  for (int rf = 0; rf < 2; ++rf) {
    #pragma unroll
    for (int n = 0; n < 4; ++n) {
      const int o = o0 + n * 16 + ln;
      const float bval = bias[o];
      #pragma unroll
      for (int r = 0; r < 4; ++r) {
        const int i = i0 + w * 32 + rf * 16 + 4 * g + r;
        out[(size_t)i * 512 + o] = acc[rf][n][r] + bval;
      }
    }
  }
}

extern "C" void kernel_launch(void* const* d_in, const int* in_sizes, int n_in,
                              void* d_out, int out_size, void* d_ws, size_t ws_size,
                              hipStream_t stream) {
  const float* query = (const float*)d_in[0];
  const float* key_  = (const float*)d_in[1];
  const float* value = (const float*)d_in[2];
  const float* pos   = (const float*)d_in[3];
  const float* Wq = (const float*)d_in[4];
  const float* bq = (const float*)d_in[5];
  const float* Wk = (const float*)d_in[6];
  const float* bk = (const float*)d_in[7];
  const float* Wv = (const float*)d_in[8];
  const float* bv = (const float*)d_in[9];
  const float* Wp = (const float*)d_in[10];
  const float* ub = (const float*)d_in[11];
  const float* vbias = (const float*)d_in[12];
  const float* Wo = (const float*)d_in[13];
  const float* bo = (const float*)d_in[14];

  char* ws = (char*)d_ws;
  unsigned short* QU  = (unsigned short*)(ws);
  unsigned short* QV  = (unsigned short*)(ws + 4194304);
  unsigned short* Kb  = (unsigned short*)(ws + 2 * 4194304);
  unsigned short* Vs  = (unsigned short*)(ws + 3 * 4194304);
  unsigned short* Pb  = (unsigned short*)(ws + 4 * 4194304);
  unsigned short* CTX = (unsigned short*)(ws + 4 * 4194304 + 2097152);

  proj_fused<<<dim3(32, 8, 4), dim3(256), 0, stream>>>(
      query, key_, value, pos, Wq, Wk, Wv, Wp, bq, bk, bv, ub, vbias,
      QU, QV, Kb, Vs, Pb);
  attn_kernel<<<dim3(64, 32), dim3(256), 0, stream>>>(QU, QV, Kb, Vs, Pb, CTX);
  out_gemm<<<dim3(32, 8), dim3(256), 0, stream>>>(CTX, Wo, bo, (float*)d_out);
}